// Round 9
// baseline (440.956 us; speedup 1.0000x reference)
//
#include <hip/hip_runtime.h>
#include <hip/hip_bf16.h>

typedef unsigned short ushort_t;
typedef __attribute__((ext_vector_type(4))) float floatx4;
typedef __attribute__((ext_vector_type(8))) __bf16 bf16x8;
typedef __attribute__((ext_vector_type(4))) unsigned short ushortx4;
typedef __attribute__((ext_vector_type(8))) unsigned short ushortx8;

// ---------- bf16 helpers ----------
static __device__ __forceinline__ float b2f(ushort_t u) {
  union { unsigned int i; float f; } v; v.i = ((unsigned int)u) << 16; return v.f;
}
static __device__ __forceinline__ ushort_t f2b(float f) {
  unsigned int x = __float_as_uint(f);
  unsigned int r = (x + 0x7fffu + ((x >> 16) & 1u)) >> 16;
  return (ushort_t)r;
}
// async global->LDS, 16B per lane (dest = wave-uniform base + lane*16)
static __device__ __forceinline__ void glds16(const ushort_t* g, ushort_t* l) {
  __builtin_amdgcn_global_load_lds(
      (const __attribute__((address_space(1))) unsigned int*)g,
      (__attribute__((address_space(3))) unsigned int*)l, 16, 0, 0);
}

// =========================================================================
// GEMM core: C[m0:+128, n0:+128] = A[M,K] @ B[N,K]^T (+bias[col]).
// bf16 MFMA, tile 128x128xBK64, 4 waves, wave 64x64 via 4x4 mfma 16x16x32.
// LDS bank-conflict fix: k-chunk XOR swizzle (slot c holds chunk c^(row&7)).
// 128^2 tile + >=2 blocks/CU is the measured-best regime (1 blk/CU -- via
// big-LDS or small-grid -- loses the m114 inter-block overlap; R4-R8).
// BSUM: B operand = bf16(f32(Bm)+f32(Bm2)) reg-staged to the same swizzled
// slots (for consuming split-K partial pairs without a combine pass).
// MODE 1: bf16 row-major [M,N] (caller folds batch offset into outB)
// MODE 2: bf16 TRANSPOSED batched: [(b*N+col)*1024 + (m&1023)], b=m>>10
// MODE 3: split-N: cols [0,512)->outB stride 512; [512,2048)->C1 stride 1536
// =========================================================================
template<int MODE, bool BSUM>
static __device__ __forceinline__ void gemm_core(
    const ushort_t* __restrict__ Ab, const ushort_t* __restrict__ Bm,
    const ushort_t* __restrict__ Bm2,
    const float* __restrict__ bias,
    ushort_t* __restrict__ outB, ushort_t* __restrict__ C1,
    int N, int K, int m0, int n0, int kbeg, int kend,
    ushort_t* As, ushort_t* Bs)
{
  const int tid  = threadIdx.x;
  const int wid  = tid >> 6;
  const int lane = tid & 63;
  const int quad = lane >> 4;
  const int l16  = lane & 15;

  const int wr = (wid >> 1) * 64;
  const int wc = (wid & 1) * 64;

  // staging: thread covers LDS slot (srow, tid&7); global source chunk is
  // XOR-swizzled: scj = (tid&7) ^ (srow&7)
  const int srow = tid >> 3;
  const int scj  = ((tid & 7) ^ (srow & 7)) * 8;
  const long abase = (long)(m0 + srow) * K + scj;
  const long bbase = (long)(n0 + srow) * K + scj;

  floatx4 acc[4][4];
#pragma unroll
  for (int i = 0; i < 4; ++i)
#pragma unroll
    for (int j = 0; j < 4; ++j) acc[i][j] = (floatx4){0.f, 0.f, 0.f, 0.f};

  const int rx = l16 & 7;   // row&7 for all fragment rows (wr,wc,i*16 mult 8)

  for (int k0 = kbeg; k0 < kend; k0 += 64) {
    __syncthreads();
#pragma unroll
    for (int p = 0; p < 4; ++p)
      glds16(Ab + abase + 32 * p * (long)K + k0, &As[tid * 8 + p * 2048]);
    if constexpr (BSUM) {
#pragma unroll
      for (int p = 0; p < 4; ++p) {
        const long gidx = bbase + 32 * p * (long)K + k0;
        ushortx8 ua = *(const ushortx8*)(Bm + gidx);
        ushortx8 ub = *(const ushortx8*)(Bm2 + gidx);
        ushortx8 o;
#pragma unroll
        for (int r = 0; r < 8; ++r) o[r] = f2b(b2f(ua[r]) + b2f(ub[r]));
        *(ushortx8*)(&Bs[tid * 8 + p * 2048]) = o;
      }
    } else {
#pragma unroll
      for (int p = 0; p < 4; ++p)
        glds16(Bm + bbase + 32 * p * (long)K + k0, &Bs[tid * 8 + p * 2048]);
    }
    __syncthreads();

#pragma unroll
    for (int kk = 0; kk < 2; ++kk) {
      bf16x8 a[4], b[4];
#pragma unroll
      for (int i = 0; i < 4; ++i)
        a[i] = *(const bf16x8*)(&As[(wr + i * 16 + l16) * 64 +
                                    (((kk * 4 + quad) ^ rx) << 3)]);
#pragma unroll
      for (int j = 0; j < 4; ++j)
        b[j] = *(const bf16x8*)(&Bs[(wc + j * 16 + l16) * 64 +
                                    (((kk * 4 + quad) ^ rx) << 3)]);
#pragma unroll
      for (int i = 0; i < 4; ++i)
#pragma unroll
        for (int j = 0; j < 4; ++j)
          acc[i][j] = __builtin_amdgcn_mfma_f32_16x16x32_bf16(a[i], b[j], acc[i][j], 0, 0, 0);
    }
  }

  // epilogue: lane = col l16; rows quad*4+r in each 16x16 sub-tile
#pragma unroll
  for (int j = 0; j < 4; ++j) {
    int col = n0 + wc + j * 16 + l16;
    float bv = (bias != nullptr) ? bias[col] : 0.f;
#pragma unroll
    for (int i = 0; i < 4; ++i) {
      int mbase = m0 + wr + i * 16 + quad * 4;
      if constexpr (MODE == 1) {
#pragma unroll
        for (int r = 0; r < 4; ++r)
          outB[(long)(mbase + r) * N + col] = f2b(acc[i][j][r] + bv);
      } else if constexpr (MODE == 2) {
        int b = mbase >> 10, jrow = mbase & 1023;
        ushortx4 pk;
#pragma unroll
        for (int r = 0; r < 4; ++r) pk[r] = f2b(acc[i][j][r] + bv);
        *(ushortx4*)(outB + ((long)b * N + col) * 1024 + jrow) = pk;
      } else {
        // MODE 3: fused x0|qkv0 split-N (n-tiles are 128-wide, so a whole
        // block is on one side of col 512)
        ushort_t* o = (n0 < 512) ? outB : C1;
        const int cw = (n0 < 512) ? 512 : 1536;
        const int cc = (n0 < 512) ? col : col - 512;
#pragma unroll
        for (int r = 0; r < 4; ++r)
          o[(long)(mbase + r) * cw + cc] = f2b(acc[i][j][r] + bv);
      }
    }
  }
}

// generic dispatcher: XCD swizzle lin = y*gridX+x; m = lin%gridY, n = lin/gridY
// KS: split-K ways; blockIdx.z = z*KS+kq; partial kq -> C{kq}; bias only kq0.
template<int MODE, int KS, bool BSUM>
__global__ __launch_bounds__(256, 3) void gemm_bt(
    const ushort_t* __restrict__ Ab, const ushort_t* __restrict__ Bm,
    const ushort_t* __restrict__ Bm2,
    const float* __restrict__ bias,
    ushort_t* __restrict__ C0, ushort_t* __restrict__ C1,
    int N, int K, long aBatch, long bBatch, long cBatch)
{
  __shared__ __align__(16) ushort_t As[128 * 64];
  __shared__ __align__(16) ushort_t Bs[128 * 64];
  const int lin = blockIdx.y * gridDim.x + blockIdx.x;
  const int m0 = (lin % gridDim.y) * 128;
  const int n0 = (lin / gridDim.y) * 128;
  const int z  = (KS > 1) ? (int)(blockIdx.z / KS) : blockIdx.z;
  const int kq = (KS > 1) ? (int)(blockIdx.z % KS) : 0;
  const int kbeg = kq * (K / KS);
  const int kend = kbeg + (K / KS);
  ushort_t* outB = (KS >= 2 && kq == 1) ? C1 : C0;
  const float* bs = (KS > 1 && kq != 0) ? nullptr : bias;
  gemm_core<MODE, BSUM>(
      Ab + (long)z * aBatch, Bm + (long)z * bBatch,
      BSUM ? (Bm2 + (long)z * bBatch) : Bm2, bs,
      outB + ((MODE == 1) ? (long)z * cBatch : 0), C1,
      N, K, m0, n0, kbeg, kend, As, Bs);
}

// setup GEMMs merged: z<3 -> Wfused[z] = Wconv[z] @ Wout[z] (512x512x512);
// z==3 -> Wq0 tail = Win0 @ Wemb (1536x256x512). Grid (24,1,4).
__global__ __launch_bounds__(256, 3) void setup_gemm(
    const ushort_t* __restrict__ Wcb, const ushort_t* __restrict__ WoT,
    ushort_t* __restrict__ Wfb,
    const ushort_t* __restrict__ Winb, const ushort_t* __restrict__ WembT,
    ushort_t* __restrict__ Wq0t)
{
  __shared__ __align__(16) ushort_t As[128 * 64];
  __shared__ __align__(16) ushort_t Bs[128 * 64];
  const int lin = blockIdx.x;
  const int z = blockIdx.z;
  if (z < 3) {
    if (lin >= 16) return;   // block-uniform exit, before any barrier
    const long off = (long)z * 262144;
    gemm_core<1, false>(Wcb + off, WoT + off, nullptr, nullptr, Wfb + off,
                        nullptr, 512, 512, (lin & 3) * 128, (lin >> 2) * 128,
                        0, 512, As, Bs);
  } else {
    gemm_core<1, false>(Winb, WembT, nullptr, nullptr, Wq0t, nullptr,
                        256, 512, (lin % 12) * 128, (lin / 12) * 128,
                        0, 512, As, Bs);
  }
}

// =========================================================================
// prep (one dispatch): fp32->bf16 conversions (Win, Wemb->Wq0 head, Wconv,
// ADJ, CF), Wout transpose, Wemb transpose, bfused, folded layer-0 bias,
// Wpool fp32 transpose.
// blocks: [0,1152) Win | [1152,1216) Wemb->Wq0 | [1216,1600) Wconv |
// [1600,5696) ADJ | [5696,6720) CF | [6720,6912) WoutT | [6912,6944) WembT |
// [6944,7328) bfuse | [7328,7712) bfq->bcat+512 | [7712,7714) bemb->bcat |
// [7714,7778) WpoolT
// =========================================================================
__global__ __launch_bounds__(256) void prep_kernel(
    const float* __restrict__ Win,  ushort_t* __restrict__ Winb,
    const float* __restrict__ Wemb, ushort_t* __restrict__ Wq0,
    const float* __restrict__ Wconv, ushort_t* __restrict__ Wcb,
    const float* __restrict__ ADJ,  ushort_t* __restrict__ ADJb,
    const float* __restrict__ CF,   ushort_t* __restrict__ CFb,
    const float* __restrict__ Wout, ushort_t* __restrict__ WoT,
    const float* __restrict__ bout, const float* __restrict__ bconv,
    float* __restrict__ bfused,
    ushort_t* __restrict__ WembT,
    const float* __restrict__ bemb, const float* __restrict__ bin0,
    float* __restrict__ bcat,
    const float* __restrict__ Wpool, float* __restrict__ WpT)
{
  __shared__ float tile[64][65];
  const int bid = blockIdx.x, tid = threadIdx.x;
  if (bid < 6720) {
    const float* src; ushort_t* dst; long i;
    if (bid < 1152)      { src = Win;   dst = Winb; i = (long)bid * 256 + tid; }
    else if (bid < 1216) { src = Wemb;  dst = Wq0;  i = (long)(bid - 1152) * 256 + tid; }
    else if (bid < 1600) { src = Wconv; dst = Wcb;  i = (long)(bid - 1216) * 256 + tid; }
    else if (bid < 5696) { src = ADJ;   dst = ADJb; i = (long)(bid - 1600) * 256 + tid; }
    else                 { src = CF;    dst = CFb;  i = (long)(bid - 5696) * 256 + tid; }
    floatx4 a = ((const floatx4*)src)[2 * i];
    floatx4 b = ((const floatx4*)src)[2 * i + 1];
    ushortx4 ha, hb;
#pragma unroll
    for (int r = 0; r < 4; ++r) { ha[r] = f2b(a[r]); hb[r] = f2b(b[r]); }
    ((ushortx4*)dst)[2 * i] = ha; ((ushortx4*)dst)[2 * i + 1] = hb;
  } else if (bid < 6912) {
    // transpose+cvt: T[l][k][j] = bf16(Wout[l][j][k])
    const int t = bid - 6720;
    const int z = t >> 6, k0 = ((t >> 3) & 7) * 64, j0 = (t & 7) * 64;
    const long base = (long)z * 262144;
#pragma unroll
    for (int p = 0; p < 16; ++p) {
      int idx = tid + p * 256;
      int jj = idx >> 6, kk = idx & 63;
      tile[jj][kk] = Wout[base + (long)(j0 + jj) * 512 + k0 + kk];
    }
    __syncthreads();
#pragma unroll
    for (int p = 0; p < 16; ++p) {
      int idx = tid + p * 256;
      int kk = idx >> 6, jj = idx & 63;
      WoT[base + (long)(k0 + kk) * 512 + j0 + jj] = f2b(tile[jj][kk]);
    }
  } else if (bid < 6944) {
    // WembT[c][h] = bf16(Wemb[h][c])  (Wemb is [512][256])
    const int t = bid - 6912;
    const int j0 = (t >> 2) * 64, k0 = (t & 3) * 64;
#pragma unroll
    for (int p = 0; p < 16; ++p) {
      int idx = tid + p * 256;
      int jj = idx >> 6, kk = idx & 63;
      tile[jj][kk] = Wemb[(long)(j0 + jj) * 256 + k0 + kk];
    }
    __syncthreads();
#pragma unroll
    for (int p = 0; p < 16; ++p) {
      int idx = tid + p * 256;
      int kk = idx >> 6, jj = idx & 63;
      WembT[(long)(k0 + kk) * 512 + j0 + jj] = f2b(tile[jj][kk]);
    }
  } else if (bid < 7328) {
    // bfused[l][o] = dot(Wconv[l][o][:], bout[l][:]) + bconv[l][o]
    const int w = tid >> 6, lane = tid & 63;
    const int gi = (bid - 6944) * 4 + w;
    const int l = gi >> 9, o = gi & 511;
    float p = 0.f;
#pragma unroll
    for (int k = 0; k < 8; ++k)
      p += Wconv[(long)l * 262144 + (long)o * 512 + lane + 64 * k] *
           bout[l * 512 + lane + 64 * k];
#pragma unroll
    for (int msk = 1; msk <= 32; msk <<= 1) p += __shfl_xor(p, msk);
    if (lane == 0) bfused[gi] = p + bconv[l * 512 + o];
  } else if (bid < 7712) {
    // bcat[512+o] = bin0[o] + dot(Win0[o][:], bemb[:])  (layer-0 bias fold)
    const int w = tid >> 6, lane = tid & 63;
    const int o = (bid - 7328) * 4 + w;
    float p = 0.f;
#pragma unroll
    for (int k = 0; k < 8; ++k)
      p += Win[(long)o * 512 + lane + 64 * k] * bemb[lane + 64 * k];
#pragma unroll
    for (int msk = 1; msk <= 32; msk <<= 1) p += __shfl_xor(p, msk);
    if (lane == 0) bcat[512 + o] = p + bin0[o];
  } else if (bid < 7714) {
    // bcat[0:512] = bemb
    int idx = (bid - 7712) * 256 + tid;
    bcat[idx] = bemb[idx];
  } else {
    // WpT[h][o] = Wpool[o][h]  (fp32, for coalesced graph dot)
    const int t = bid - 7714;
    const int j0 = (t >> 3) * 64, k0 = (t & 7) * 64;   // j=o tile, k=h tile
#pragma unroll
    for (int p = 0; p < 16; ++p) {
      int idx = tid + p * 256;
      int jj = idx >> 6, kk = idx & 63;
      tile[jj][kk] = Wpool[(long)(j0 + jj) * 512 + k0 + kk];
    }
    __syncthreads();
#pragma unroll
    for (int p = 0; p < 16; ++p) {
      int idx = tid + p * 256;
      int kk = idx >> 6, jj = idx & 63;
      WpT[(long)(k0 + kk) * 512 + j0 + jj] = tile[jj][kk];
    }
  }
}

// =========================================================================
// Attention over batch axis. Block (512 thr) per node n; qkv staged in LDS
// as bf16 (source already bf16 -> lossless), ~27 KB -> 4 blocks/CU, grid
// 1024 fully resident. Wave = head. Stride 1544 puts the 8 Q/K row bases
// on 8 distinct banks.
// =========================================================================
__global__ __launch_bounds__(512, 8) void attn_kernel(
    const ushort_t* __restrict__ qkv, ushort_t* __restrict__ outp)
{
  __shared__ ushort_t qs[8 * 1544];
  __shared__ float aw[8][64];
  const int tid = threadIdx.x;
  const int n = blockIdx.x;

  const ushort_t* src = qkv + (long)n * 1536;
#pragma unroll
  for (int p = 0; p < 3; ++p) {
    int c = tid + p * 512;
    int i = c / 192, off = (c % 192) * 8;
    *(ushortx8*)(&qs[i * 1544 + off]) =
        *(const ushortx8*)(src + (long)i * 1024 * 1536 + off);
  }
  __syncthreads();

  const int h    = tid >> 6;
  const int lane = tid & 63;
  const int i = lane >> 3, j = lane & 7;
  const ushort_t* qrow = &qs[i * 1544 + h * 64];
  const ushort_t* krow = &qs[j * 1544 + 512 + h * 64];
  float s = 0.f;
#pragma unroll
  for (int c8 = 0; c8 < 8; ++c8) {
    ushortx8 qa = *(const ushortx8*)(qrow + c8 * 8);
    ushortx8 ka = *(const ushortx8*)(krow + c8 * 8);
#pragma unroll
    for (int r = 0; r < 8; ++r) s += b2f(qa[r]) * b2f(ka[r]);
  }
  s *= 0.125f;

  float m = s;
  m = fmaxf(m, __shfl_xor(m, 1));
  m = fmaxf(m, __shfl_xor(m, 2));
  m = fmaxf(m, __shfl_xor(m, 4));
  float e = __expf(s - m);
  float sum = e;
  sum += __shfl_xor(sum, 1);
  sum += __shfl_xor(sum, 2);
  sum += __shfl_xor(sum, 4);
  aw[h][lane] = e / sum;   // written+read by the same wave; no barrier needed

  // PV: hoist v into regs (channel = h*64 + lane)
  float vv[8];
#pragma unroll
  for (int jj = 0; jj < 8; ++jj)
    vv[jj] = b2f(qs[jj * 1544 + 1024 + h * 64 + lane]);
  const long ob = (long)n * 512 + h * 64 + lane;
#pragma unroll
  for (int ii = 0; ii < 8; ++ii) {
    float acc = 0.f;
#pragma unroll
    for (int jj = 0; jj < 8; ++jj) acc += aw[h][ii * 8 + jj] * vv[jj];
    outp[ob + (long)ii * 1024 * 512] = f2b(acc);
  }
}

// =========================================================================
// x_out(bf16) = LayerNorm(x + aggA+aggB). Wave per row (512); 16B/lane
// vectorized loads/stores (lane owns elements [lane*8, lane*8+8)).
// =========================================================================
__global__ __launch_bounds__(256) void ln_kernel(
    const ushort_t* __restrict__ xb,
    const ushort_t* __restrict__ aggA, const ushort_t* __restrict__ aggB,
    ushort_t* __restrict__ outB)
{
  const int w = threadIdx.x >> 6, lane = threadIdx.x & 63;
  const long base = ((long)blockIdx.x * 4 + w) * 512 + lane * 8;
  ushortx8 ux = *(const ushortx8*)(xb + base);
  ushortx8 ua = *(const ushortx8*)(aggA + base);
  ushortx8 ub = *(const ushortx8*)(aggB + base);
  float v[8];
  float s = 0.f;
#pragma unroll
  for (int k = 0; k < 8; ++k) {
    v[k] = b2f(ux[k]) + b2f(ua[k]) + b2f(ub[k]);
    s += v[k];
  }
#pragma unroll
  for (int msk = 1; msk <= 32; msk <<= 1) s += __shfl_xor(s, msk);
  float mean = s * (1.f / 512.f);
  float vv = 0.f;
#pragma unroll
  for (int k = 0; k < 8; ++k) { float d = v[k] - mean; vv += d * d; }
#pragma unroll
  for (int msk = 1; msk <= 32; msk <<= 1) vv += __shfl_xor(vv, msk);
  float inv = rsqrtf(vv * (1.f / 512.f) + 1e-5f);
  ushortx8 o;
#pragma unroll
  for (int k = 0; k < 8; ++k) o[k] = f2b((v[k] - mean) * inv);
  *(ushortx8*)(outB + base) = o;
}

// =========================================================================
// Final layer: LN -> out_x (fp32) + fused heads (mastery, diff, h1, h2)
// + per-block pool partials xp[2048][512].  16B/lane vectorized.
// =========================================================================
__global__ __launch_bounds__(256) void final_ln_heads_kernel(
    const ushort_t* __restrict__ xb,
    const ushort_t* __restrict__ aggA, const ushort_t* __restrict__ aggB,
    float* __restrict__ out_x,
    const float* __restrict__ Wcls, const float* __restrict__ bcls,
    const float* __restrict__ Wdiff, const float* __restrict__ bdiff,
    const float* __restrict__ Wpre,
    float* __restrict__ mastery, float* __restrict__ diff,
    float* __restrict__ h1, float* __restrict__ h2,
    float* __restrict__ xp)
{
  __shared__ float sp4[4][512];
  const int w = threadIdx.x >> 6, lane = threadIdx.x & 63;
  const long row = (long)blockIdx.x * 4 + w;
  const long base = row * 512 + lane * 8;
  ushortx8 ux = *(const ushortx8*)(xb + base);
  ushortx8 ua = *(const ushortx8*)(aggA + base);
  ushortx8 ub = *(const ushortx8*)(aggB + base);
  float v[8];
  float s = 0.f;
#pragma unroll
  for (int k = 0; k < 8; ++k) {
    v[k] = b2f(ux[k]) + b2f(ua[k]) + b2f(ub[k]);
    s += v[k];
  }
#pragma unroll
  for (int msk = 1; msk <= 32; msk <<= 1) s += __shfl_xor(s, msk);
  float mean = s * (1.f / 512.f);
  float vv = 0.f;
#pragma unroll
  for (int k = 0; k < 8; ++k) { float d = v[k] - mean; vv += d * d; }
#pragma unroll
  for (int msk = 1; msk <= 32; msk <<= 1) vv += __shfl_xor(vv, msk);
  float inv = rsqrtf(vv * (1.f / 512.f) + 1e-5f);
  floatx4 o0, o1;
#pragma unroll
  for (int k = 0; k < 4; ++k) { v[k] = (v[k] - mean) * inv; o0[k] = v[k]; }
#pragma unroll
  for (int k = 0; k < 4; ++k) { v[4 + k] = (v[4 + k] - mean) * inv; o1[k] = v[4 + k]; }
  *(floatx4*)(out_x + base) = o0;
  *(floatx4*)(out_x + base + 4) = o1;
  *(floatx4*)(&sp4[w][lane * 8]) = o0;
  *(floatx4*)(&sp4[w][lane * 8 + 4]) = o1;
  __syncthreads();
  // block pool partial: sum of this block's 4 rows (256 blocks/batch)
  for (int t = threadIdx.x; t < 512; t += 256)
    xp[(long)blockIdx.x * 512 + t] =
        sp4[0][t] + sp4[1][t] + sp4[2][t] + sp4[3][t];
#pragma unroll
  for (int o = 0; o < 8; ++o) {
    const float* wp = (o == 0) ? Wcls
                    : (o <= 5) ? (Wdiff + (o - 1) * 512)
                    : (o == 6) ? Wpre : (Wpre + 512);
    floatx4 wa = *(const floatx4*)(wp + lane * 8);
    floatx4 wb = *(const floatx4*)(wp + lane * 8 + 4);
    float p = 0.f;
#pragma unroll
    for (int k = 0; k < 4; ++k) p += v[k] * wa[k];
#pragma unroll
    for (int k = 0; k < 4; ++k) p += v[4 + k] * wb[k];
#pragma unroll
    for (int msk = 1; msk <= 32; msk <<= 1) p += __shfl_xor(p, msk);
    if (lane == 0) {
      if (o == 0)      mastery[row] = p + bcls[0];
      else if (o <= 5) diff[row * 5 + (o - 1)] = p + bdiff[o - 1];
      else if (o == 6) h1[row] = p;
      else             h2[row] = p;
    }
  }
}

// =========================================================================
// epilogue: [0,8184) prereq as flat aligned float4 stream
//   (t = b*1047552 + i*1023 + pos; i,pos via const-div; j = pos + (pos>=i)),
// [8184,8248) xq partial pool reduce: xq[b*8+qg][c] = sum of 32 xp rows.
// =========================================================================
__global__ __launch_bounds__(256) void epi_kernel(
    const float* __restrict__ h1, const float* __restrict__ h2,
    const float* __restrict__ bpre, float* __restrict__ outp,
    const float* __restrict__ xp, float* __restrict__ xq)
{
  const int bid = blockIdx.x;
  if (bid < 8184) {
    const int g = bid * 256 + threadIdx.x;
    const int t = g * 4;                     // global fp32 index, 16B aligned
    const int b = t / 1047552;               // 1024*1023
    const int r = t - b * 1047552;
    const float bp = bpre[0];
    const float* h1b = h1 + b * 1024;
    const float* h2b = h2 + b * 1024;
    floatx4 o;
#pragma unroll
    for (int k = 0; k < 4; ++k) {
      int rk = r + k;                        // stays within batch (1047552%4==0)
      int i = rk / 1023;
      int pos = rk - i * 1023;
      int j = pos + (pos >= i);
      o[k] = h1b[i] + bp + h2b[j];
    }
    *(floatx4*)(outp + t) = o;
  } else {
    const int q0 = bid - 8184;               // (b,qg): b=q0>>3, qg=q0&7
    const float* p = xp + (long)q0 * 32 * 512;
#pragma unroll
    for (int cc = 0; cc < 2; ++cc) {
      int c = threadIdx.x + cc * 256;
      float s = 0.f;
#pragma unroll
      for (int q = 0; q < 32; ++q) s += p[q * 512 + c];
      xq[(long)q0 * 512 + c] = s;
    }
  }
}

// graph[b,o] = (sum_p xq[b*8+p][:]/1024) . WpT[:,o] + b_pool[o]
// 8 blocks x 256 thr; WpT access coalesced across lanes, xms LDS broadcast.
__global__ __launch_bounds__(256) void graph_kernel(
    const float* __restrict__ xq, const float* __restrict__ WpT,
    const float* __restrict__ bpool, float* __restrict__ g)
{
  __shared__ float xms[512];
  const int b = blockIdx.x;
  const float* xb = xq + (long)b * 8 * 512;
#pragma unroll
  for (int cc = 0; cc < 2; ++cc) {
    int c = threadIdx.x + cc * 256;
    float s = 0.f;
#pragma unroll
    for (int p = 0; p < 8; ++p) s += xb[p * 512 + c];
    xms[c] = s;
  }
  __syncthreads();
#pragma unroll
  for (int oo = 0; oo < 2; ++oo) {
    int o = threadIdx.x + oo * 256;
    float acc = 0.f;
    for (int h = 0; h < 512; ++h) acc += xms[h] * WpT[h * 512 + o];
    g[b * 512 + o] = acc * (1.f / 1024.f) + bpool[o];
  }
}

// =========================================================================
extern "C" void kernel_launch(void* const* d_in, const int* in_sizes, int n_in,
                              void* d_out, int out_size, void* d_ws, size_t ws_size,
                              hipStream_t stream)
{
  const float* CF    = (const float*)d_in[0];
  const float* ADJ   = (const float*)d_in[1];
  const float* Wemb  = (const float*)d_in[4];
  const float* bemb  = (const float*)d_in[5];
  const float* Win   = (const float*)d_in[6];
  const float* bin   = (const float*)d_in[7];
  const float* Wout  = (const float*)d_in[8];
  const float* bout  = (const float*)d_in[9];
  const float* Wconv = (const float*)d_in[10];
  const float* bconv = (const float*)d_in[11];
  const float* Wcls  = (const float*)d_in[12];
  const float* bcls  = (const float*)d_in[13];
  const float* Wdiff = (const float*)d_in[14];
  const float* bdiff = (const float*)d_in[15];
  const float* Wpre  = (const float*)d_in[16];
  const float* bpre  = (const float*)d_in[17];
  const float* Wpool = (const float*)d_in[18];
  const float* bpool = (const float*)d_in[19];

  // ---- workspace layout (ushort units). Total ~72 MB (< proven 84 MB). ----
  ushort_t* W = (ushort_t*)d_ws;
  ushort_t* xb   = W;                       // 4194304
  ushort_t* qkvb = W + 4194304;             // 12582912 (end 16777216)
  // aliases inside the qkv region (dead when their user runs):
  ushort_t* cTa   = qkvb;                   // 4194304 (conv split-K part 0)
  ushort_t* aggA  = qkvb + 4194304;         // 4194304 (agg split-K part 0)
  ushort_t* aggB  = qkvb + 8388608;         // 4194304 (agg split-K part 1)
  // precompute scratch overlays aggA/B region (dead before qkv0 GEMM):
  ushort_t* WoT   = qkvb + 4194304;         // 786432
  ushort_t* Wcb   = qkvb + 4980736;         // 786432
  ushort_t* WembT = qkvb + 5767168;         // 131072 (end 5898240 < 8388608)
  // persistent:
  ushort_t* Winb = W + 16777216;            // 2359296
  ushort_t* Wfb  = W + 19136512;            // 786432 (fused Wconv@Wout)
  ushort_t* ADJb = W + 19922944;            // 8388608 (end 28311552)
  ushort_t* CFb  = W + 28311552;            // 4194304 (end 32505856)
  ushort_t* Wq0  = W + 32505856;            // 524288 (rows 0-511 Wemb, 512-2047 Win0@Wemb)
  float* bfused = (float*)(W + 33030144);   // 1536
  float* bcat   = bfused + 1536;            // 2048 (bemb ++ folded qkv0 bias)
  float* h1     = bcat + 2048;              // 8192
  float* h2     = h1 + 8192;                // 8192
  float* xp     = h2 + 8192;                // 1048576 (pool partials, 2048x512)
  float* xq     = xp + 1048576;             // 32768  (pool partials, 64x512)
  float* WpT    = xq + 32768;               // 262144 (Wpool transposed, fp32)

  // ---- output layout (fp32 concat) + d_out-as-scratch aliases ----
  float* out_x       = (float*)d_out;       // 4194304
  float* out_mastery = out_x + 4194304;     // 8192
  float* out_diff    = out_mastery + 8192;  // 40960
  float* out_prereq  = out_diff + 40960;    // 8380416
  float* out_graph   = out_prereq + 8380416;// 4096
  // attn-out bf16 scratch in out_x region (dead before final LN writes it):
  ushort_t* aob = (ushort_t*)out_x;         // 4194304 ushorts
  // conv split-K part 1 in out_prereq region (epi writes prereq at the end):
  ushort_t* cTb = (ushort_t*)out_prereq;    // 4194304 ushorts (8.4MB < 33.5MB)

  dim3 blk(256);

  // ---- precompute: one dispatch + one merged setup-GEMM dispatch ----
  prep_kernel<<<dim3(7778), blk, 0, stream>>>(
      Win, Winb, Wemb, Wq0, Wconv, Wcb, ADJ, ADJb, CF, CFb,
      Wout, WoT, bout, bconv, bfused, WembT, bemb, bin, bcat,
      Wpool, WpT);
  setup_gemm<<<dim3(24, 1, 4), blk, 0, stream>>>(
      Wcb, WoT, Wfb, Winb, WembT, Wq0 + 512 * 256);

  for (int l = 0; l < 3; ++l) {
    // qkv = x @ Win[l]^T + bin[l]   (128^2-tile GEMMs, 3 blocks/CU)
    if (l == 0) {
      // fused x0|qkv0: [xb | qkvb] = CFb @ Wq0^T + bcat  (8192 x 2048 x 256)
      gemm_bt<3, 1, false><<<dim3(16, 64, 1), blk, 0, stream>>>(
          CFb, Wq0, nullptr, bcat, xb, qkvb, 2048, 256, 0, 0, 0);
    } else {
      gemm_bt<1, 1, false><<<dim3(12, 64, 1), blk, 0, stream>>>(
          xb, Winb + (long)l * 786432, nullptr, bin + l * 1536,
          qkvb, nullptr, 1536, 512, 0, 0, 0);
    }
    // attention over batch axis -> aob (out_x scratch)
    attn_kernel<<<dim3(1024), dim3(512), 0, stream>>>(qkvb, aob);
    // convT = (ao @ Wfused[l]^T + bfused[l]) transposed, split-K=2
    // (512 blocks = 2/CU; was 256 = 1/CU, the occupancy outlier)
    gemm_bt<2, 2, false><<<dim3(4, 64, 2), blk, 0, stream>>>(
        aob, Wfb + (long)l * 262144, nullptr, bfused + l * 512,
        cTa, cTb, 512, 512, 0, 0, 0);
    // agg[b] = adj[b] @ (cTa+cTb)[b]  (batched 1024x512x1024, split-K=2;
    // B staged as reg-summed conv partials)
    gemm_bt<1, 2, true><<<dim3(4, 8, 16), blk, 0, stream>>>(
        ADJb, cTa, cTb, nullptr, aggA, aggB,
        512, 1024, 1048576, 524288, 524288);
    // x = LN(x + aggA + aggB)
    if (l < 2)
      ln_kernel<<<dim3(2048), blk, 0, stream>>>(xb, aggA, aggB, xb);
    else
      final_ln_heads_kernel<<<dim3(2048), blk, 0, stream>>>(
          xb, aggA, aggB, out_x, Wcls, bcls, Wdiff, bdiff, Wpre,
          out_mastery, out_diff, h1, h2, xp);
  }

  epi_kernel<<<dim3(8248), blk, 0, stream>>>(h1, h2, bpre, out_prereq,
                                             xp, xq);
  graph_kernel<<<dim3(8), blk, 0, stream>>>(xq, WpT, bpool, out_graph);
}

// Round 10
// 440.185 us; speedup vs baseline: 1.0018x; 1.0018x over previous
//
#include <hip/hip_runtime.h>
#include <hip/hip_bf16.h>

typedef unsigned short ushort_t;
typedef __attribute__((ext_vector_type(4))) float floatx4;
typedef __attribute__((ext_vector_type(8))) __bf16 bf16x8;
typedef __attribute__((ext_vector_type(4))) unsigned short ushortx4;
typedef __attribute__((ext_vector_type(8))) unsigned short ushortx8;

// ---------- bf16 helpers ----------
static __device__ __forceinline__ float b2f(ushort_t u) {
  union { unsigned int i; float f; } v; v.i = ((unsigned int)u) << 16; return v.f;
}
static __device__ __forceinline__ ushort_t f2b(float f) {
  unsigned int x = __float_as_uint(f);
  unsigned int r = (x + 0x7fffu + ((x >> 16) & 1u)) >> 16;
  return (ushort_t)r;
}
// async global->LDS, 16B per lane (dest = wave-uniform base + lane*16)
static __device__ __forceinline__ void glds16(const ushort_t* g, ushort_t* l) {
  __builtin_amdgcn_global_load_lds(
      (const __attribute__((address_space(1))) unsigned int*)g,
      (__attribute__((address_space(3))) unsigned int*)l, 16, 0, 0);
}

// =========================================================================
// GEMM core: C[m0:+128, n0:+128] = A[M,K] @ B[N,K]^T (+bias[col]).
// bf16 MFMA, tile 128x128xBK64, 4 waves, wave 64x64 via 4x4 mfma 16x16x32.
// LDS bank-conflict fix: k-chunk XOR swizzle (slot c holds chunk c^(row&7)).
// Both A and B staged via glds16 ONLY (R9 lesson: reg-staged B = +25% dur).
// 128^2 tile + >=2 blocks/CU is the measured-best regime.
// MODE 1: bf16 row-major [M,N] (caller folds batch offset into outB)
// MODE 2: bf16 TRANSPOSED batched: [(b*N+col)*1024 + (m&1023)], b=m>>10
// MODE 3: split-N: cols [0,512)->outB stride 512; [512,2048)->C1 stride 1536
// =========================================================================
template<int MODE>
static __device__ __forceinline__ void gemm_core(
    const ushort_t* __restrict__ Ab, const ushort_t* __restrict__ Bm,
    const float* __restrict__ bias,
    ushort_t* __restrict__ outB, ushort_t* __restrict__ C1,
    int N, int K, int m0, int n0, int kbeg, int kend,
    ushort_t* As, ushort_t* Bs)
{
  const int tid  = threadIdx.x;
  const int wid  = tid >> 6;
  const int lane = tid & 63;
  const int quad = lane >> 4;
  const int l16  = lane & 15;

  const int wr = (wid >> 1) * 64;
  const int wc = (wid & 1) * 64;

  // staging: thread covers LDS slot (srow, tid&7); global source chunk is
  // XOR-swizzled: scj = (tid&7) ^ (srow&7)
  const int srow = tid >> 3;
  const int scj  = ((tid & 7) ^ (srow & 7)) * 8;
  const long abase = (long)(m0 + srow) * K + scj;
  const long bbase = (long)(n0 + srow) * K + scj;

  floatx4 acc[4][4];
#pragma unroll
  for (int i = 0; i < 4; ++i)
#pragma unroll
    for (int j = 0; j < 4; ++j) acc[i][j] = (floatx4){0.f, 0.f, 0.f, 0.f};

  const int rx = l16 & 7;   // row&7 for all fragment rows (wr,wc,i*16 mult 8)

  for (int k0 = kbeg; k0 < kend; k0 += 64) {
    __syncthreads();
#pragma unroll
    for (int p = 0; p < 4; ++p)
      glds16(Ab + abase + 32 * p * (long)K + k0, &As[tid * 8 + p * 2048]);
#pragma unroll
    for (int p = 0; p < 4; ++p)
      glds16(Bm + bbase + 32 * p * (long)K + k0, &Bs[tid * 8 + p * 2048]);
    __syncthreads();

#pragma unroll
    for (int kk = 0; kk < 2; ++kk) {
      bf16x8 a[4], b[4];
#pragma unroll
      for (int i = 0; i < 4; ++i)
        a[i] = *(const bf16x8*)(&As[(wr + i * 16 + l16) * 64 +
                                    (((kk * 4 + quad) ^ rx) << 3)]);
#pragma unroll
      for (int j = 0; j < 4; ++j)
        b[j] = *(const bf16x8*)(&Bs[(wc + j * 16 + l16) * 64 +
                                    (((kk * 4 + quad) ^ rx) << 3)]);
#pragma unroll
      for (int i = 0; i < 4; ++i)
#pragma unroll
        for (int j = 0; j < 4; ++j)
          acc[i][j] = __builtin_amdgcn_mfma_f32_16x16x32_bf16(a[i], b[j], acc[i][j], 0, 0, 0);
    }
  }

  // epilogue: lane = col l16; rows quad*4+r in each 16x16 sub-tile
#pragma unroll
  for (int j = 0; j < 4; ++j) {
    int col = n0 + wc + j * 16 + l16;
    float bv = (bias != nullptr) ? bias[col] : 0.f;
#pragma unroll
    for (int i = 0; i < 4; ++i) {
      int mbase = m0 + wr + i * 16 + quad * 4;
      if constexpr (MODE == 1) {
#pragma unroll
        for (int r = 0; r < 4; ++r)
          outB[(long)(mbase + r) * N + col] = f2b(acc[i][j][r] + bv);
      } else if constexpr (MODE == 2) {
        int b = mbase >> 10, jrow = mbase & 1023;
        ushortx4 pk;
#pragma unroll
        for (int r = 0; r < 4; ++r) pk[r] = f2b(acc[i][j][r] + bv);
        *(ushortx4*)(outB + ((long)b * N + col) * 1024 + jrow) = pk;
      } else {
        // MODE 3: fused x0|qkv0 split-N (n-tiles are 128-wide, so a whole
        // block is on one side of col 512)
        ushort_t* o = (n0 < 512) ? outB : C1;
        const int cw = (n0 < 512) ? 512 : 1536;
        const int cc = (n0 < 512) ? col : col - 512;
#pragma unroll
        for (int r = 0; r < 4; ++r)
          o[(long)(mbase + r) * cw + cc] = f2b(acc[i][j][r] + bv);
      }
    }
  }
}

// generic dispatcher: XCD swizzle lin = y*gridX+x; m = lin%gridY, n = lin/gridY
// KS: split-K ways (1/2/4); blockIdx.z = z*KS+kq; partial kq -> C{kq}.
template<int MODE, int KS>
__global__ __launch_bounds__(256, 3) void gemm_bt(
    const ushort_t* __restrict__ Ab, const ushort_t* __restrict__ Bm,
    const float* __restrict__ bias,
    ushort_t* __restrict__ C0, ushort_t* __restrict__ C1,
    ushort_t* __restrict__ C2, ushort_t* __restrict__ C3,
    int N, int K, long aBatch, long bBatch, long cBatch)
{
  __shared__ __align__(16) ushort_t As[128 * 64];
  __shared__ __align__(16) ushort_t Bs[128 * 64];
  const int lin = blockIdx.y * gridDim.x + blockIdx.x;
  const int m0 = (lin % gridDim.y) * 128;
  const int n0 = (lin / gridDim.y) * 128;
  const int z  = (KS > 1) ? (int)(blockIdx.z / KS) : blockIdx.z;
  const int kq = (KS > 1) ? (int)(blockIdx.z % KS) : 0;
  const int kbeg = kq * (K / KS);
  const int kend = kbeg + (K / KS);
  ushort_t* outB = C0;
  if (KS >= 2 && kq == 1) outB = C1;
  if (KS >= 4 && kq == 2) outB = C2;
  if (KS >= 4 && kq == 3) outB = C3;
  gemm_core<MODE>(Ab + (long)z * aBatch, Bm + (long)z * bBatch, bias,
                  outB + ((MODE == 1) ? (long)z * cBatch : 0), C1,
                  N, K, m0, n0, kbeg, kend, As, Bs);
}

// setup GEMMs merged: z<3 -> Wfused[z] = Wconv[z] @ Wout[z] (512x512x512);
// z==3 -> Wq0 tail = Win0 @ Wemb (1536x256x512). Grid (24,1,4).
__global__ __launch_bounds__(256, 3) void setup_gemm(
    const ushort_t* __restrict__ Wcb, const ushort_t* __restrict__ WoT,
    ushort_t* __restrict__ Wfb,
    const ushort_t* __restrict__ Winb, const ushort_t* __restrict__ WembT,
    ushort_t* __restrict__ Wq0t)
{
  __shared__ __align__(16) ushort_t As[128 * 64];
  __shared__ __align__(16) ushort_t Bs[128 * 64];
  const int lin = blockIdx.x;
  const int z = blockIdx.z;
  if (z < 3) {
    if (lin >= 16) return;   // block-uniform exit, before any barrier
    const long off = (long)z * 262144;
    gemm_core<1>(Wcb + off, WoT + off, nullptr, Wfb + off, nullptr,
                 512, 512, (lin & 3) * 128, (lin >> 2) * 128, 0, 512, As, Bs);
  } else {
    gemm_core<1>(Winb, WembT, nullptr, Wq0t, nullptr,
                 256, 512, (lin % 12) * 128, (lin / 12) * 128, 0, 512, As, Bs);
  }
}

// =========================================================================
// prep (one dispatch): fp32->bf16 conversions (Win, Wemb->Wq0 head, Wconv,
// ADJ, CF), Wout transpose, Wemb transpose, bfused, folded layer-0 bias,
// Wpool fp32 transpose.
// blocks: [0,1152) Win | [1152,1216) Wemb->Wq0 | [1216,1600) Wconv |
// [1600,5696) ADJ | [5696,6720) CF | [6720,6912) WoutT | [6912,6944) WembT |
// [6944,7328) bfuse | [7328,7712) bfq->bcat+512 | [7712,7714) bemb->bcat |
// [7714,7778) WpoolT
// =========================================================================
__global__ __launch_bounds__(256) void prep_kernel(
    const float* __restrict__ Win,  ushort_t* __restrict__ Winb,
    const float* __restrict__ Wemb, ushort_t* __restrict__ Wq0,
    const float* __restrict__ Wconv, ushort_t* __restrict__ Wcb,
    const float* __restrict__ ADJ,  ushort_t* __restrict__ ADJb,
    const float* __restrict__ CF,   ushort_t* __restrict__ CFb,
    const float* __restrict__ Wout, ushort_t* __restrict__ WoT,
    const float* __restrict__ bout, const float* __restrict__ bconv,
    float* __restrict__ bfused,
    ushort_t* __restrict__ WembT,
    const float* __restrict__ bemb, const float* __restrict__ bin0,
    float* __restrict__ bcat,
    const float* __restrict__ Wpool, float* __restrict__ WpT)
{
  __shared__ float tile[64][65];
  const int bid = blockIdx.x, tid = threadIdx.x;
  if (bid < 6720) {
    const float* src; ushort_t* dst; long i;
    if (bid < 1152)      { src = Win;   dst = Winb; i = (long)bid * 256 + tid; }
    else if (bid < 1216) { src = Wemb;  dst = Wq0;  i = (long)(bid - 1152) * 256 + tid; }
    else if (bid < 1600) { src = Wconv; dst = Wcb;  i = (long)(bid - 1216) * 256 + tid; }
    else if (bid < 5696) { src = ADJ;   dst = ADJb; i = (long)(bid - 1600) * 256 + tid; }
    else                 { src = CF;    dst = CFb;  i = (long)(bid - 5696) * 256 + tid; }
    floatx4 a = ((const floatx4*)src)[2 * i];
    floatx4 b = ((const floatx4*)src)[2 * i + 1];
    ushortx4 ha, hb;
#pragma unroll
    for (int r = 0; r < 4; ++r) { ha[r] = f2b(a[r]); hb[r] = f2b(b[r]); }
    ((ushortx4*)dst)[2 * i] = ha; ((ushortx4*)dst)[2 * i + 1] = hb;
  } else if (bid < 6912) {
    // transpose+cvt: T[l][k][j] = bf16(Wout[l][j][k])
    const int t = bid - 6720;
    const int z = t >> 6, k0 = ((t >> 3) & 7) * 64, j0 = (t & 7) * 64;
    const long base = (long)z * 262144;
#pragma unroll
    for (int p = 0; p < 16; ++p) {
      int idx = tid + p * 256;
      int jj = idx >> 6, kk = idx & 63;
      tile[jj][kk] = Wout[base + (long)(j0 + jj) * 512 + k0 + kk];
    }
    __syncthreads();
#pragma unroll
    for (int p = 0; p < 16; ++p) {
      int idx = tid + p * 256;
      int kk = idx >> 6, jj = idx & 63;
      WoT[base + (long)(k0 + kk) * 512 + j0 + jj] = f2b(tile[jj][kk]);
    }
  } else if (bid < 6944) {
    // WembT[c][h] = bf16(Wemb[h][c])  (Wemb is [512][256])
    const int t = bid - 6912;
    const int j0 = (t >> 2) * 64, k0 = (t & 3) * 64;
#pragma unroll
    for (int p = 0; p < 16; ++p) {
      int idx = tid + p * 256;
      int jj = idx >> 6, kk = idx & 63;
      tile[jj][kk] = Wemb[(long)(j0 + jj) * 256 + k0 + kk];
    }
    __syncthreads();
#pragma unroll
    for (int p = 0; p < 16; ++p) {
      int idx = tid + p * 256;
      int kk = idx >> 6, jj = idx & 63;
      WembT[(long)(k0 + kk) * 512 + j0 + jj] = f2b(tile[jj][kk]);
    }
  } else if (bid < 7328) {
    // bfused[l][o] = dot(Wconv[l][o][:], bout[l][:]) + bconv[l][o]
    const int w = tid >> 6, lane = tid & 63;
    const int gi = (bid - 6944) * 4 + w;
    const int l = gi >> 9, o = gi & 511;
    float p = 0.f;
#pragma unroll
    for (int k = 0; k < 8; ++k)
      p += Wconv[(long)l * 262144 + (long)o * 512 + lane + 64 * k] *
           bout[l * 512 + lane + 64 * k];
#pragma unroll
    for (int msk = 1; msk <= 32; msk <<= 1) p += __shfl_xor(p, msk);
    if (lane == 0) bfused[gi] = p + bconv[l * 512 + o];
  } else if (bid < 7712) {
    // bcat[512+o] = bin0[o] + dot(Win0[o][:], bemb[:])  (layer-0 bias fold)
    const int w = tid >> 6, lane = tid & 63;
    const int o = (bid - 7328) * 4 + w;
    float p = 0.f;
#pragma unroll
    for (int k = 0; k < 8; ++k)
      p += Win[(long)o * 512 + lane + 64 * k] * bemb[lane + 64 * k];
#pragma unroll
    for (int msk = 1; msk <= 32; msk <<= 1) p += __shfl_xor(p, msk);
    if (lane == 0) bcat[512 + o] = p + bin0[o];
  } else if (bid < 7714) {
    // bcat[0:512] = bemb
    int idx = (bid - 7712) * 256 + tid;
    bcat[idx] = bemb[idx];
  } else {
    // WpT[h][o] = Wpool[o][h]  (fp32, for coalesced graph dot)
    const int t = bid - 7714;
    const int j0 = (t >> 3) * 64, k0 = (t & 7) * 64;   // j=o tile, k=h tile
#pragma unroll
    for (int p = 0; p < 16; ++p) {
      int idx = tid + p * 256;
      int jj = idx >> 6, kk = idx & 63;
      tile[jj][kk] = Wpool[(long)(j0 + jj) * 512 + k0 + kk];
    }
    __syncthreads();
#pragma unroll
    for (int p = 0; p < 16; ++p) {
      int idx = tid + p * 256;
      int kk = idx >> 6, jj = idx & 63;
      WpT[(long)(k0 + kk) * 512 + j0 + jj] = tile[jj][kk];
    }
  }
}

// =========================================================================
// Attention over batch axis. Block (512 thr) per node n; qkv staged in LDS
// as bf16 (source already bf16 -> lossless), ~27 KB -> 4 blocks/CU, grid
// 1024 fully resident. Wave = head. Stride 1544 puts the 8 Q/K row bases
// on 8 distinct banks.
// =========================================================================
__global__ __launch_bounds__(512, 8) void attn_kernel(
    const ushort_t* __restrict__ qkv, ushort_t* __restrict__ outp)
{
  __shared__ ushort_t qs[8 * 1544];
  __shared__ float aw[8][64];
  const int tid = threadIdx.x;
  const int n = blockIdx.x;

  const ushort_t* src = qkv + (long)n * 1536;
#pragma unroll
  for (int p = 0; p < 3; ++p) {
    int c = tid + p * 512;
    int i = c / 192, off = (c % 192) * 8;
    *(ushortx8*)(&qs[i * 1544 + off]) =
        *(const ushortx8*)(src + (long)i * 1024 * 1536 + off);
  }
  __syncthreads();

  const int h    = tid >> 6;
  const int lane = tid & 63;
  const int i = lane >> 3, j = lane & 7;
  const ushort_t* qrow = &qs[i * 1544 + h * 64];
  const ushort_t* krow = &qs[j * 1544 + 512 + h * 64];
  float s = 0.f;
#pragma unroll
  for (int c8 = 0; c8 < 8; ++c8) {
    ushortx8 qa = *(const ushortx8*)(qrow + c8 * 8);
    ushortx8 ka = *(const ushortx8*)(krow + c8 * 8);
#pragma unroll
    for (int r = 0; r < 8; ++r) s += b2f(qa[r]) * b2f(ka[r]);
  }
  s *= 0.125f;

  float m = s;
  m = fmaxf(m, __shfl_xor(m, 1));
  m = fmaxf(m, __shfl_xor(m, 2));
  m = fmaxf(m, __shfl_xor(m, 4));
  float e = __expf(s - m);
  float sum = e;
  sum += __shfl_xor(sum, 1);
  sum += __shfl_xor(sum, 2);
  sum += __shfl_xor(sum, 4);
  aw[h][lane] = e / sum;   // written+read by the same wave; no barrier needed

  // PV: hoist v into regs (channel = h*64 + lane)
  float vv[8];
#pragma unroll
  for (int jj = 0; jj < 8; ++jj)
    vv[jj] = b2f(qs[jj * 1544 + 1024 + h * 64 + lane]);
  const long ob = (long)n * 512 + h * 64 + lane;
#pragma unroll
  for (int ii = 0; ii < 8; ++ii) {
    float acc = 0.f;
#pragma unroll
    for (int jj = 0; jj < 8; ++jj) acc += aw[h][ii * 8 + jj] * vv[jj];
    outp[ob + (long)ii * 1024 * 512] = f2b(acc);
  }
}

// =========================================================================
// x_out(bf16) = LayerNorm(x + aggA+aggB+aggC+aggD). Wave per row (512);
// 16B/lane vectorized loads/stores.
// =========================================================================
__global__ __launch_bounds__(256) void ln_kernel(
    const ushort_t* __restrict__ xb,
    const ushort_t* __restrict__ aggA, const ushort_t* __restrict__ aggB,
    const ushort_t* __restrict__ aggC, const ushort_t* __restrict__ aggD,
    ushort_t* __restrict__ outB)
{
  const int w = threadIdx.x >> 6, lane = threadIdx.x & 63;
  const long base = ((long)blockIdx.x * 4 + w) * 512 + lane * 8;
  ushortx8 ux = *(const ushortx8*)(xb + base);
  ushortx8 ua = *(const ushortx8*)(aggA + base);
  ushortx8 ub = *(const ushortx8*)(aggB + base);
  ushortx8 uc = *(const ushortx8*)(aggC + base);
  ushortx8 ud = *(const ushortx8*)(aggD + base);
  float v[8];
  float s = 0.f;
#pragma unroll
  for (int k = 0; k < 8; ++k) {
    v[k] = b2f(ux[k]) + b2f(ua[k]) + b2f(ub[k]) + b2f(uc[k]) + b2f(ud[k]);
    s += v[k];
  }
#pragma unroll
  for (int msk = 1; msk <= 32; msk <<= 1) s += __shfl_xor(s, msk);
  float mean = s * (1.f / 512.f);
  float vv = 0.f;
#pragma unroll
  for (int k = 0; k < 8; ++k) { float d = v[k] - mean; vv += d * d; }
#pragma unroll
  for (int msk = 1; msk <= 32; msk <<= 1) vv += __shfl_xor(vv, msk);
  float inv = rsqrtf(vv * (1.f / 512.f) + 1e-5f);
  ushortx8 o;
#pragma unroll
  for (int k = 0; k < 8; ++k) o[k] = f2b((v[k] - mean) * inv);
  *(ushortx8*)(outB + base) = o;
}

// =========================================================================
// Final layer: LN -> out_x (fp32) + fused heads (mastery, diff, h1, h2)
// + per-block pool partials xp[2048][512].  16B/lane vectorized.
// =========================================================================
__global__ __launch_bounds__(256) void final_ln_heads_kernel(
    const ushort_t* __restrict__ xb,
    const ushort_t* __restrict__ aggA, const ushort_t* __restrict__ aggB,
    const ushort_t* __restrict__ aggC, const ushort_t* __restrict__ aggD,
    float* __restrict__ out_x,
    const float* __restrict__ Wcls, const float* __restrict__ bcls,
    const float* __restrict__ Wdiff, const float* __restrict__ bdiff,
    const float* __restrict__ Wpre,
    float* __restrict__ mastery, float* __restrict__ diff,
    float* __restrict__ h1, float* __restrict__ h2,
    float* __restrict__ xp)
{
  __shared__ float sp4[4][512];
  const int w = threadIdx.x >> 6, lane = threadIdx.x & 63;
  const long row = (long)blockIdx.x * 4 + w;
  const long base = row * 512 + lane * 8;
  ushortx8 ux = *(const ushortx8*)(xb + base);
  ushortx8 ua = *(const ushortx8*)(aggA + base);
  ushortx8 ub = *(const ushortx8*)(aggB + base);
  ushortx8 uc = *(const ushortx8*)(aggC + base);
  ushortx8 ud = *(const ushortx8*)(aggD + base);
  float v[8];
  float s = 0.f;
#pragma unroll
  for (int k = 0; k < 8; ++k) {
    v[k] = b2f(ux[k]) + b2f(ua[k]) + b2f(ub[k]) + b2f(uc[k]) + b2f(ud[k]);
    s += v[k];
  }
#pragma unroll
  for (int msk = 1; msk <= 32; msk <<= 1) s += __shfl_xor(s, msk);
  float mean = s * (1.f / 512.f);
  float vv = 0.f;
#pragma unroll
  for (int k = 0; k < 8; ++k) { float d = v[k] - mean; vv += d * d; }
#pragma unroll
  for (int msk = 1; msk <= 32; msk <<= 1) vv += __shfl_xor(vv, msk);
  float inv = rsqrtf(vv * (1.f / 512.f) + 1e-5f);
  floatx4 o0, o1;
#pragma unroll
  for (int k = 0; k < 4; ++k) { v[k] = (v[k] - mean) * inv; o0[k] = v[k]; }
#pragma unroll
  for (int k = 0; k < 4; ++k) { v[4 + k] = (v[4 + k] - mean) * inv; o1[k] = v[4 + k]; }
  *(floatx4*)(out_x + base) = o0;
  *(floatx4*)(out_x + base + 4) = o1;
  *(floatx4*)(&sp4[w][lane * 8]) = o0;
  *(floatx4*)(&sp4[w][lane * 8 + 4]) = o1;
  __syncthreads();
  // block pool partial: sum of this block's 4 rows (256 blocks/batch)
  for (int t = threadIdx.x; t < 512; t += 256)
    xp[(long)blockIdx.x * 512 + t] =
        sp4[0][t] + sp4[1][t] + sp4[2][t] + sp4[3][t];
#pragma unroll
  for (int o = 0; o < 8; ++o) {
    const float* wp = (o == 0) ? Wcls
                    : (o <= 5) ? (Wdiff + (o - 1) * 512)
                    : (o == 6) ? Wpre : (Wpre + 512);
    floatx4 wa = *(const floatx4*)(wp + lane * 8);
    floatx4 wb = *(const floatx4*)(wp + lane * 8 + 4);
    float p = 0.f;
#pragma unroll
    for (int k = 0; k < 4; ++k) p += v[k] * wa[k];
#pragma unroll
    for (int k = 0; k < 4; ++k) p += v[4 + k] * wb[k];
#pragma unroll
    for (int msk = 1; msk <= 32; msk <<= 1) p += __shfl_xor(p, msk);
    if (lane == 0) {
      if (o == 0)      mastery[row] = p + bcls[0];
      else if (o <= 5) diff[row * 5 + (o - 1)] = p + bdiff[o - 1];
      else if (o == 6) h1[row] = p;
      else             h2[row] = p;
    }
  }
}

// =========================================================================
// epilogue: [0,8184) prereq as flat aligned float4 stream
//   (t = b*1047552 + i*1023 + pos; i,pos via const-div; j = pos + (pos>=i)),
// [8184,8248) xq partial pool reduce: xq[b*8+qg][c] = sum of 32 xp rows.
// =========================================================================
__global__ __launch_bounds__(256) void epi_kernel(
    const float* __restrict__ h1, const float* __restrict__ h2,
    const float* __restrict__ bpre, float* __restrict__ outp,
    const float* __restrict__ xp, float* __restrict__ xq)
{
  const int bid = blockIdx.x;
  if (bid < 8184) {
    const int g = bid * 256 + threadIdx.x;
    const int t = g * 4;                     // global fp32 index, 16B aligned
    const int b = t / 1047552;               // 1024*1023
    const int r = t - b * 1047552;
    const float bp = bpre[0];
    const float* h1b = h1 + b * 1024;
    const float* h2b = h2 + b * 1024;
    floatx4 o;
#pragma unroll
    for (int k = 0; k < 4; ++k) {
      int rk = r + k;                        // stays within batch (1047552%4==0)
      int i = rk / 1023;
      int pos = rk - i * 1023;
      int j = pos + (pos >= i);
      o[k] = h1b[i] + bp + h2b[j];
    }
    *(floatx4*)(outp + t) = o;
  } else {
    const int q0 = bid - 8184;               // (b,qg): b=q0>>3, qg=q0&7
    const float* p = xp + (long)q0 * 32 * 512;
#pragma unroll
    for (int cc = 0; cc < 2; ++cc) {
      int c = threadIdx.x + cc * 256;
      float s = 0.f;
#pragma unroll
      for (int q = 0; q < 32; ++q) s += p[q * 512 + c];
      xq[(long)q0 * 512 + c] = s;
    }
  }
}

// graph[b,o] = (sum_p xq[b*8+p][:]/1024) . WpT[:,o] + b_pool[o]
// 8 blocks x 256 thr; WpT access coalesced across lanes, xms LDS broadcast.
__global__ __launch_bounds__(256) void graph_kernel(
    const float* __restrict__ xq, const float* __restrict__ WpT,
    const float* __restrict__ bpool, float* __restrict__ g)
{
  __shared__ float xms[512];
  const int b = blockIdx.x;
  const float* xb = xq + (long)b * 8 * 512;
#pragma unroll
  for (int cc = 0; cc < 2; ++cc) {
    int c = threadIdx.x + cc * 256;
    float s = 0.f;
#pragma unroll
    for (int p = 0; p < 8; ++p) s += xb[p * 512 + c];
    xms[c] = s;
  }
  __syncthreads();
#pragma unroll
  for (int oo = 0; oo < 2; ++oo) {
    int o = threadIdx.x + oo * 256;
    float acc = 0.f;
    for (int h = 0; h < 512; ++h) acc += xms[h] * WpT[h * 512 + o];
    g[b * 512 + o] = acc * (1.f / 1024.f) + bpool[o];
  }
}

// =========================================================================
extern "C" void kernel_launch(void* const* d_in, const int* in_sizes, int n_in,
                              void* d_out, int out_size, void* d_ws, size_t ws_size,
                              hipStream_t stream)
{
  const float* CF    = (const float*)d_in[0];
  const float* ADJ   = (const float*)d_in[1];
  const float* Wemb  = (const float*)d_in[4];
  const float* bemb  = (const float*)d_in[5];
  const float* Win   = (const float*)d_in[6];
  const float* bin   = (const float*)d_in[7];
  const float* Wout  = (const float*)d_in[8];
  const float* bout  = (const float*)d_in[9];
  const float* Wconv = (const float*)d_in[10];
  const float* bconv = (const float*)d_in[11];
  const float* Wcls  = (const float*)d_in[12];
  const float* bcls  = (const float*)d_in[13];
  const float* Wdiff = (const float*)d_in[14];
  const float* bdiff = (const float*)d_in[15];
  const float* Wpre  = (const float*)d_in[16];
  const float* bpre  = (const float*)d_in[17];
  const float* Wpool = (const float*)d_in[18];
  const float* bpool = (const float*)d_in[19];

  // ---- workspace layout (ushort units). Total ~72 MB (< proven 84 MB). ----
  ushort_t* W = (ushort_t*)d_ws;
  ushort_t* xb   = W;                       // 4194304
  ushort_t* qkvb = W + 4194304;             // 12582912 (end 16777216)
  // aliases inside the qkv region (dead when their user runs):
  ushort_t* cT    = qkvb;                   // 4194304 (conv out, post-attn)
  ushort_t* aggA  = qkvb + 4194304;         // 4194304 (agg split-K part 0)
  ushort_t* aggB  = qkvb + 8388608;         // 4194304 (agg split-K part 1)
  // precompute scratch overlays aggA/B region (dead before qkv0 GEMM):
  ushort_t* WoT   = qkvb + 4194304;         // 786432
  ushort_t* Wcb   = qkvb + 4980736;         // 786432
  ushort_t* WembT = qkvb + 5767168;         // 131072 (end 5898240 < 8388608)
  // persistent:
  ushort_t* Winb = W + 16777216;            // 2359296
  ushort_t* Wfb  = W + 19136512;            // 786432 (fused Wconv@Wout)
  ushort_t* ADJb = W + 19922944;            // 8388608 (end 28311552)
  ushort_t* CFb  = W + 28311552;            // 4194304 (end 32505856)
  ushort_t* Wq0  = W + 32505856;            // 524288 (rows 0-511 Wemb, 512-2047 Win0@Wemb)
  float* bfused = (float*)(W + 33030144);   // 1536
  float* bcat   = bfused + 1536;            // 2048 (bemb ++ folded qkv0 bias)
  float* h1     = bcat + 2048;              // 8192
  float* h2     = h1 + 8192;                // 8192
  float* xp     = h2 + 8192;                // 1048576 (pool partials, 2048x512)
  float* xq     = xp + 1048576;             // 32768  (pool partials, 64x512)
  float* WpT    = xq + 32768;               // 262144 (Wpool transposed, fp32)

  // ---- output layout (fp32 concat) + d_out-as-scratch aliases ----
  float* out_x       = (float*)d_out;       // 4194304
  float* out_mastery = out_x + 4194304;     // 8192
  float* out_diff    = out_mastery + 8192;  // 40960
  float* out_prereq  = out_diff + 40960;    // 8380416
  float* out_graph   = out_prereq + 8380416;// 4096
  // attn-out bf16 scratch in out_x region (dead before final LN writes it):
  ushort_t* aob = (ushort_t*)out_x;         // 4194304 ushorts
  // agg split-K parts 2,3 in out_prereq region (epi writes prereq at end):
  ushort_t* aggC = (ushort_t*)out_prereq;            // 4194304
  ushort_t* aggD = (ushort_t*)out_prereq + 4194304;  // 4194304 (16.8M<33.5M ok)

  dim3 blk(256);

  // ---- precompute: one dispatch + one merged setup-GEMM dispatch ----
  prep_kernel<<<dim3(7778), blk, 0, stream>>>(
      Win, Winb, Wemb, Wq0, Wconv, Wcb, ADJ, ADJb, CF, CFb,
      Wout, WoT, bout, bconv, bfused, WembT, bemb, bin, bcat,
      Wpool, WpT);
  setup_gemm<<<dim3(24, 1, 4), blk, 0, stream>>>(
      Wcb, WoT, Wfb, Winb, WembT, Wq0 + 512 * 256);

  for (int l = 0; l < 3; ++l) {
    // qkv = x @ Win[l]^T + bin[l]   (128^2-tile GEMMs, 3 blocks/CU)
    if (l == 0) {
      // fused x0|qkv0: [xb | qkvb] = CFb @ Wq0^T + bcat  (8192 x 2048 x 256)
      gemm_bt<3, 1><<<dim3(16, 64, 1), blk, 0, stream>>>(
          CFb, Wq0, bcat, xb, qkvb, nullptr, nullptr, 2048, 256, 0, 0, 0);
    } else {
      gemm_bt<1, 1><<<dim3(12, 64, 1), blk, 0, stream>>>(
          xb, Winb + (long)l * 786432, bin + l * 1536,
          qkvb, nullptr, nullptr, nullptr, 1536, 512, 0, 0, 0);
    }
    // attention over batch axis -> aob (out_x scratch)
    attn_kernel<<<dim3(1024), dim3(512), 0, stream>>>(qkvb, aob);
    // convT = (ao @ Wfused[l]^T + bfused[l]) transposed (qkv region dead)
    gemm_bt<2, 1><<<dim3(4, 64, 1), blk, 0, stream>>>(
        aob, Wfb + (long)l * 262144, bfused + l * 512,
        cT, nullptr, nullptr, nullptr, 512, 512, 0, 0, 0);
    // agg[b] = adj[b] @ conv[b]  (batched 1024x512x1024, split-K=4:
    // 1024 blocks -> the latency-bound kernel gets 2x resident waves)
    gemm_bt<1, 4><<<dim3(4, 8, 32), blk, 0, stream>>>(
        ADJb, cT, nullptr, aggA, aggB, aggC, aggD,
        512, 1024, 1048576, 524288, 524288);
    // x = LN(x + aggA + aggB + aggC + aggD)
    if (l < 2)
      ln_kernel<<<dim3(2048), blk, 0, stream>>>(xb, aggA, aggB, aggC, aggD, xb);
    else
      final_ln_heads_kernel<<<dim3(2048), blk, 0, stream>>>(
          xb, aggA, aggB, aggC, aggD, out_x, Wcls, bcls, Wdiff, bdiff, Wpre,
          out_mastery, out_diff, h1, h2, xp);
  }

  epi_kernel<<<dim3(8248), blk, 0, stream>>>(h1, h2, bpre, out_prereq,
                                             xp, xq);
  graph_kernel<<<dim3(8), blk, 0, stream>>>(xq, WpT, bpool, out_graph);
}

// Round 11
// 416.638 us; speedup vs baseline: 1.0584x; 1.0565x over previous
//
#include <hip/hip_runtime.h>
#include <hip/hip_bf16.h>

typedef unsigned short ushort_t;
typedef __attribute__((ext_vector_type(4))) float floatx4;
typedef __attribute__((ext_vector_type(8))) __bf16 bf16x8;
typedef __attribute__((ext_vector_type(4))) unsigned short ushortx4;
typedef __attribute__((ext_vector_type(8))) unsigned short ushortx8;

// ---------- bf16 helpers ----------
static __device__ __forceinline__ float b2f(ushort_t u) {
  union { unsigned int i; float f; } v; v.i = ((unsigned int)u) << 16; return v.f;
}
static __device__ __forceinline__ ushort_t f2b(float f) {
  unsigned int x = __float_as_uint(f);
  unsigned int r = (x + 0x7fffu + ((x >> 16) & 1u)) >> 16;
  return (ushort_t)r;
}
// async global->LDS, 16B per lane (dest = wave-uniform base + lane*16)
static __device__ __forceinline__ void glds16(const ushort_t* g, ushort_t* l) {
  __builtin_amdgcn_global_load_lds(
      (const __attribute__((address_space(1))) unsigned int*)g,
      (__attribute__((address_space(3))) unsigned int*)l, 16, 0, 0);
}

// =========================================================================
// GEMM core: C[m0:+MT, n0:+128] = A[M,K] @ B[N,K]^T (+bias[col]).
// bf16 MFMA, tile MTx128xBK64, 4 waves, mfma 16x16x32.
// MT=128: wave 64x64 (acc 4x4).  MT=64: wave 32x64 (acc 2x4) — halves the
// tile to DOUBLE the block count at identical HBM traffic (R10 lesson:
// occupancy bought with partial-traffic loses; bought with tiling wins).
// Per-element K-accumulation order is MT-independent -> bit-identical.
// LDS bank-conflict fix: k-chunk XOR swizzle (slot c holds chunk c^(row&7)).
// Both A and B staged via glds16 ONLY (R9: reg-staged B = +25% dur).
// MODE 1: bf16 row-major [M,N] (caller folds batch offset into outB)
// MODE 2: bf16 TRANSPOSED batched: [(b*N+col)*1024 + (m&1023)], b=m>>10
// MODE 3: split-N: cols [0,512)->outB stride 512; [512,2048)->C1 stride 1536
// =========================================================================
template<int MODE, int MT>
static __device__ __forceinline__ void gemm_core(
    const ushort_t* __restrict__ Ab, const ushort_t* __restrict__ Bm,
    const float* __restrict__ bias,
    ushort_t* __restrict__ outB, ushort_t* __restrict__ C1,
    int N, int K, int m0, int n0, int kbeg, int kend,
    ushort_t* As, ushort_t* Bs)
{
  constexpr int MI = MT / 32;          // m-frags per wave (4 or 2)
  const int tid  = threadIdx.x;
  const int wid  = tid >> 6;
  const int lane = tid & 63;
  const int quad = lane >> 4;
  const int l16  = lane & 15;

  const int wr = (wid >> 1) * (MT / 2);
  const int wc = (wid & 1) * 64;

  // staging: thread covers LDS slot (srow, tid&7); global source chunk is
  // XOR-swizzled: scj = (tid&7) ^ (srow&7)
  const int srow = tid >> 3;
  const int scj  = ((tid & 7) ^ (srow & 7)) * 8;
  const long abase = (long)(m0 + srow) * K + scj;
  const long bbase = (long)(n0 + srow) * K + scj;

  floatx4 acc[MI][4];
#pragma unroll
  for (int i = 0; i < MI; ++i)
#pragma unroll
    for (int j = 0; j < 4; ++j) acc[i][j] = (floatx4){0.f, 0.f, 0.f, 0.f};

  const int rx = l16 & 7;   // row&7 for all fragment rows (wr,wc,i*16 mult 8)

  for (int k0 = kbeg; k0 < kend; k0 += 64) {
    __syncthreads();
#pragma unroll
    for (int p = 0; p < MT / 32; ++p)
      glds16(Ab + abase + 32 * p * (long)K + k0, &As[tid * 8 + p * 2048]);
#pragma unroll
    for (int p = 0; p < 4; ++p)
      glds16(Bm + bbase + 32 * p * (long)K + k0, &Bs[tid * 8 + p * 2048]);
    __syncthreads();

#pragma unroll
    for (int kk = 0; kk < 2; ++kk) {
      bf16x8 a[MI], b[4];
#pragma unroll
      for (int i = 0; i < MI; ++i)
        a[i] = *(const bf16x8*)(&As[(wr + i * 16 + l16) * 64 +
                                    (((kk * 4 + quad) ^ rx) << 3)]);
#pragma unroll
      for (int j = 0; j < 4; ++j)
        b[j] = *(const bf16x8*)(&Bs[(wc + j * 16 + l16) * 64 +
                                    (((kk * 4 + quad) ^ rx) << 3)]);
#pragma unroll
      for (int i = 0; i < MI; ++i)
#pragma unroll
        for (int j = 0; j < 4; ++j)
          acc[i][j] = __builtin_amdgcn_mfma_f32_16x16x32_bf16(a[i], b[j], acc[i][j], 0, 0, 0);
    }
  }

  // epilogue: lane = col l16; rows quad*4+r in each 16x16 sub-tile
#pragma unroll
  for (int j = 0; j < 4; ++j) {
    int col = n0 + wc + j * 16 + l16;
    float bv = (bias != nullptr) ? bias[col] : 0.f;
#pragma unroll
    for (int i = 0; i < MI; ++i) {
      int mbase = m0 + wr + i * 16 + quad * 4;
      if constexpr (MODE == 1) {
#pragma unroll
        for (int r = 0; r < 4; ++r)
          outB[(long)(mbase + r) * N + col] = f2b(acc[i][j][r] + bv);
      } else if constexpr (MODE == 2) {
        int b = mbase >> 10, jrow = mbase & 1023;
        ushortx4 pk;
#pragma unroll
        for (int r = 0; r < 4; ++r) pk[r] = f2b(acc[i][j][r] + bv);
        *(ushortx4*)(outB + ((long)b * N + col) * 1024 + jrow) = pk;
      } else {
        // MODE 3: fused x0|qkv0 split-N (n-tiles are 128-wide, so a whole
        // block is on one side of col 512)
        ushort_t* o = (n0 < 512) ? outB : C1;
        const int cw = (n0 < 512) ? 512 : 1536;
        const int cc = (n0 < 512) ? col : col - 512;
#pragma unroll
        for (int r = 0; r < 4; ++r)
          o[(long)(mbase + r) * cw + cc] = f2b(acc[i][j][r] + bv);
      }
    }
  }
}

// generic dispatcher: XCD swizzle lin = y*gridX+x; m = lin%gridY, n = lin/gridY
// KS: split-K ways (1/2); blockIdx.z = z*KS+kq; partial kq -> C{kq}.
template<int MODE, int KS, int MT>
__global__ __launch_bounds__(256, 3) void gemm_bt(
    const ushort_t* __restrict__ Ab, const ushort_t* __restrict__ Bm,
    const float* __restrict__ bias,
    ushort_t* __restrict__ C0, ushort_t* __restrict__ C1,
    int N, int K, long aBatch, long bBatch, long cBatch)
{
  __shared__ __align__(16) ushort_t As[MT * 64];
  __shared__ __align__(16) ushort_t Bs[128 * 64];
  const int lin = blockIdx.y * gridDim.x + blockIdx.x;
  const int m0 = (lin % gridDim.y) * MT;
  const int n0 = (lin / gridDim.y) * 128;
  const int z  = (KS > 1) ? (int)(blockIdx.z / KS) : blockIdx.z;
  const int kq = (KS > 1) ? (int)(blockIdx.z % KS) : 0;
  const int kbeg = kq * (K / KS);
  const int kend = kbeg + (K / KS);
  ushort_t* outB = (KS >= 2 && kq == 1) ? C1 : C0;
  gemm_core<MODE, MT>(Ab + (long)z * aBatch, Bm + (long)z * bBatch, bias,
                      outB + ((MODE == 1) ? (long)z * cBatch : 0), C1,
                      N, K, m0, n0, kbeg, kend, As, Bs);
}

// setup GEMMs merged: z<3 -> Wfused[z] = Wconv[z] @ Wout[z] (512x512x512);
// z==3 -> Wq0 tail = Win0 @ Wemb (1536x256x512). Grid (24,1,4).
__global__ __launch_bounds__(256, 3) void setup_gemm(
    const ushort_t* __restrict__ Wcb, const ushort_t* __restrict__ WoT,
    ushort_t* __restrict__ Wfb,
    const ushort_t* __restrict__ Winb, const ushort_t* __restrict__ WembT,
    ushort_t* __restrict__ Wq0t)
{
  __shared__ __align__(16) ushort_t As[128 * 64];
  __shared__ __align__(16) ushort_t Bs[128 * 64];
  const int lin = blockIdx.x;
  const int z = blockIdx.z;
  if (z < 3) {
    if (lin >= 16) return;   // block-uniform exit, before any barrier
    const long off = (long)z * 262144;
    gemm_core<1, 128>(Wcb + off, WoT + off, nullptr, Wfb + off, nullptr,
                      512, 512, (lin & 3) * 128, (lin >> 2) * 128, 0, 512,
                      As, Bs);
  } else {
    gemm_core<1, 128>(Winb, WembT, nullptr, Wq0t, nullptr,
                      256, 512, (lin % 12) * 128, (lin / 12) * 128, 0, 512,
                      As, Bs);
  }
}

// =========================================================================
// prep (one dispatch): fp32->bf16 conversions (Win, Wemb->Wq0 head, Wconv,
// ADJ, CF), Wout transpose, Wemb transpose, bfused, folded layer-0 bias,
// Wpool fp32 transpose.
// blocks: [0,1152) Win | [1152,1216) Wemb->Wq0 | [1216,1600) Wconv |
// [1600,5696) ADJ | [5696,6720) CF | [6720,6912) WoutT | [6912,6944) WembT |
// [6944,7328) bfuse | [7328,7712) bfq->bcat+512 | [7712,7714) bemb->bcat |
// [7714,7778) WpoolT
// =========================================================================
__global__ __launch_bounds__(256) void prep_kernel(
    const float* __restrict__ Win,  ushort_t* __restrict__ Winb,
    const float* __restrict__ Wemb, ushort_t* __restrict__ Wq0,
    const float* __restrict__ Wconv, ushort_t* __restrict__ Wcb,
    const float* __restrict__ ADJ,  ushort_t* __restrict__ ADJb,
    const float* __restrict__ CF,   ushort_t* __restrict__ CFb,
    const float* __restrict__ Wout, ushort_t* __restrict__ WoT,
    const float* __restrict__ bout, const float* __restrict__ bconv,
    float* __restrict__ bfused,
    ushort_t* __restrict__ WembT,
    const float* __restrict__ bemb, const float* __restrict__ bin0,
    float* __restrict__ bcat,
    const float* __restrict__ Wpool, float* __restrict__ WpT)
{
  __shared__ float tile[64][65];
  const int bid = blockIdx.x, tid = threadIdx.x;
  if (bid < 6720) {
    const float* src; ushort_t* dst; long i;
    if (bid < 1152)      { src = Win;   dst = Winb; i = (long)bid * 256 + tid; }
    else if (bid < 1216) { src = Wemb;  dst = Wq0;  i = (long)(bid - 1152) * 256 + tid; }
    else if (bid < 1600) { src = Wconv; dst = Wcb;  i = (long)(bid - 1216) * 256 + tid; }
    else if (bid < 5696) { src = ADJ;   dst = ADJb; i = (long)(bid - 1600) * 256 + tid; }
    else                 { src = CF;    dst = CFb;  i = (long)(bid - 5696) * 256 + tid; }
    floatx4 a = ((const floatx4*)src)[2 * i];
    floatx4 b = ((const floatx4*)src)[2 * i + 1];
    ushortx4 ha, hb;
#pragma unroll
    for (int r = 0; r < 4; ++r) { ha[r] = f2b(a[r]); hb[r] = f2b(b[r]); }
    ((ushortx4*)dst)[2 * i] = ha; ((ushortx4*)dst)[2 * i + 1] = hb;
  } else if (bid < 6912) {
    // transpose+cvt: T[l][k][j] = bf16(Wout[l][j][k])
    const int t = bid - 6720;
    const int z = t >> 6, k0 = ((t >> 3) & 7) * 64, j0 = (t & 7) * 64;
    const long base = (long)z * 262144;
#pragma unroll
    for (int p = 0; p < 16; ++p) {
      int idx = tid + p * 256;
      int jj = idx >> 6, kk = idx & 63;
      tile[jj][kk] = Wout[base + (long)(j0 + jj) * 512 + k0 + kk];
    }
    __syncthreads();
#pragma unroll
    for (int p = 0; p < 16; ++p) {
      int idx = tid + p * 256;
      int kk = idx >> 6, jj = idx & 63;
      WoT[base + (long)(k0 + kk) * 512 + j0 + jj] = f2b(tile[jj][kk]);
    }
  } else if (bid < 6944) {
    // WembT[c][h] = bf16(Wemb[h][c])  (Wemb is [512][256])
    const int t = bid - 6912;
    const int j0 = (t >> 2) * 64, k0 = (t & 3) * 64;
#pragma unroll
    for (int p = 0; p < 16; ++p) {
      int idx = tid + p * 256;
      int jj = idx >> 6, kk = idx & 63;
      tile[jj][kk] = Wemb[(long)(j0 + jj) * 256 + k0 + kk];
    }
    __syncthreads();
#pragma unroll
    for (int p = 0; p < 16; ++p) {
      int idx = tid + p * 256;
      int kk = idx >> 6, jj = idx & 63;
      WembT[(long)(k0 + kk) * 512 + j0 + jj] = f2b(tile[jj][kk]);
    }
  } else if (bid < 7328) {
    // bfused[l][o] = dot(Wconv[l][o][:], bout[l][:]) + bconv[l][o]
    const int w = tid >> 6, lane = tid & 63;
    const int gi = (bid - 6944) * 4 + w;
    const int l = gi >> 9, o = gi & 511;
    float p = 0.f;
#pragma unroll
    for (int k = 0; k < 8; ++k)
      p += Wconv[(long)l * 262144 + (long)o * 512 + lane + 64 * k] *
           bout[l * 512 + lane + 64 * k];
#pragma unroll
    for (int msk = 1; msk <= 32; msk <<= 1) p += __shfl_xor(p, msk);
    if (lane == 0) bfused[gi] = p + bconv[l * 512 + o];
  } else if (bid < 7712) {
    // bcat[512+o] = bin0[o] + dot(Win0[o][:], bemb[:])  (layer-0 bias fold)
    const int w = tid >> 6, lane = tid & 63;
    const int o = (bid - 7328) * 4 + w;
    float p = 0.f;
#pragma unroll
    for (int k = 0; k < 8; ++k)
      p += Win[(long)o * 512 + lane + 64 * k] * bemb[lane + 64 * k];
#pragma unroll
    for (int msk = 1; msk <= 32; msk <<= 1) p += __shfl_xor(p, msk);
    if (lane == 0) bcat[512 + o] = p + bin0[o];
  } else if (bid < 7714) {
    // bcat[0:512] = bemb
    int idx = (bid - 7712) * 256 + tid;
    bcat[idx] = bemb[idx];
  } else {
    // WpT[h][o] = Wpool[o][h]  (fp32, for coalesced graph dot)
    const int t = bid - 7714;
    const int j0 = (t >> 3) * 64, k0 = (t & 7) * 64;   // j=o tile, k=h tile
#pragma unroll
    for (int p = 0; p < 16; ++p) {
      int idx = tid + p * 256;
      int jj = idx >> 6, kk = idx & 63;
      tile[jj][kk] = Wpool[(long)(j0 + jj) * 512 + k0 + kk];
    }
    __syncthreads();
#pragma unroll
    for (int p = 0; p < 16; ++p) {
      int idx = tid + p * 256;
      int kk = idx >> 6, jj = idx & 63;
      WpT[(long)(k0 + kk) * 512 + j0 + jj] = tile[jj][kk];
    }
  }
}

// =========================================================================
// Attention over batch axis. Block (512 thr) per node n; qkv staged in LDS
// as bf16 (source already bf16 -> lossless), ~27 KB -> 4 blocks/CU, grid
// 1024 fully resident. Wave = head. Stride 1544 puts the 8 Q/K row bases
// on 8 distinct banks.
// =========================================================================
__global__ __launch_bounds__(512, 8) void attn_kernel(
    const ushort_t* __restrict__ qkv, ushort_t* __restrict__ outp)
{
  __shared__ ushort_t qs[8 * 1544];
  __shared__ float aw[8][64];
  const int tid = threadIdx.x;
  const int n = blockIdx.x;

  const ushort_t* src = qkv + (long)n * 1536;
#pragma unroll
  for (int p = 0; p < 3; ++p) {
    int c = tid + p * 512;
    int i = c / 192, off = (c % 192) * 8;
    *(ushortx8*)(&qs[i * 1544 + off]) =
        *(const ushortx8*)(src + (long)i * 1024 * 1536 + off);
  }
  __syncthreads();

  const int h    = tid >> 6;
  const int lane = tid & 63;
  const int i = lane >> 3, j = lane & 7;
  const ushort_t* qrow = &qs[i * 1544 + h * 64];
  const ushort_t* krow = &qs[j * 1544 + 512 + h * 64];
  float s = 0.f;
#pragma unroll
  for (int c8 = 0; c8 < 8; ++c8) {
    ushortx8 qa = *(const ushortx8*)(qrow + c8 * 8);
    ushortx8 ka = *(const ushortx8*)(krow + c8 * 8);
#pragma unroll
    for (int r = 0; r < 8; ++r) s += b2f(qa[r]) * b2f(ka[r]);
  }
  s *= 0.125f;

  float m = s;
  m = fmaxf(m, __shfl_xor(m, 1));
  m = fmaxf(m, __shfl_xor(m, 2));
  m = fmaxf(m, __shfl_xor(m, 4));
  float e = __expf(s - m);
  float sum = e;
  sum += __shfl_xor(sum, 1);
  sum += __shfl_xor(sum, 2);
  sum += __shfl_xor(sum, 4);
  aw[h][lane] = e / sum;   // written+read by the same wave; no barrier needed

  // PV: hoist v into regs (channel = h*64 + lane)
  float vv[8];
#pragma unroll
  for (int jj = 0; jj < 8; ++jj)
    vv[jj] = b2f(qs[jj * 1544 + 1024 + h * 64 + lane]);
  const long ob = (long)n * 512 + h * 64 + lane;
#pragma unroll
  for (int ii = 0; ii < 8; ++ii) {
    float acc = 0.f;
#pragma unroll
    for (int jj = 0; jj < 8; ++jj) acc += aw[h][ii * 8 + jj] * vv[jj];
    outp[ob + (long)ii * 1024 * 512] = f2b(acc);
  }
}

// =========================================================================
// x_out(bf16) = LayerNorm(x + aggA+aggB). Wave per row (512); 16B/lane
// vectorized loads/stores (lane owns elements [lane*8, lane*8+8)).
// =========================================================================
__global__ __launch_bounds__(256) void ln_kernel(
    const ushort_t* __restrict__ xb,
    const ushort_t* __restrict__ aggA, const ushort_t* __restrict__ aggB,
    ushort_t* __restrict__ outB)
{
  const int w = threadIdx.x >> 6, lane = threadIdx.x & 63;
  const long base = ((long)blockIdx.x * 4 + w) * 512 + lane * 8;
  ushortx8 ux = *(const ushortx8*)(xb + base);
  ushortx8 ua = *(const ushortx8*)(aggA + base);
  ushortx8 ub = *(const ushortx8*)(aggB + base);
  float v[8];
  float s = 0.f;
#pragma unroll
  for (int k = 0; k < 8; ++k) {
    v[k] = b2f(ux[k]) + b2f(ua[k]) + b2f(ub[k]);
    s += v[k];
  }
#pragma unroll
  for (int msk = 1; msk <= 32; msk <<= 1) s += __shfl_xor(s, msk);
  float mean = s * (1.f / 512.f);
  float vv = 0.f;
#pragma unroll
  for (int k = 0; k < 8; ++k) { float d = v[k] - mean; vv += d * d; }
#pragma unroll
  for (int msk = 1; msk <= 32; msk <<= 1) vv += __shfl_xor(vv, msk);
  float inv = rsqrtf(vv * (1.f / 512.f) + 1e-5f);
  ushortx8 o;
#pragma unroll
  for (int k = 0; k < 8; ++k) o[k] = f2b((v[k] - mean) * inv);
  *(ushortx8*)(outB + base) = o;
}

// =========================================================================
// Final layer: LN -> out_x (fp32) + fused heads (mastery, diff, h1, h2)
// + per-block pool partials xp[2048][512].  16B/lane vectorized.
// =========================================================================
__global__ __launch_bounds__(256) void final_ln_heads_kernel(
    const ushort_t* __restrict__ xb,
    const ushort_t* __restrict__ aggA, const ushort_t* __restrict__ aggB,
    float* __restrict__ out_x,
    const float* __restrict__ Wcls, const float* __restrict__ bcls,
    const float* __restrict__ Wdiff, const float* __restrict__ bdiff,
    const float* __restrict__ Wpre,
    float* __restrict__ mastery, float* __restrict__ diff,
    float* __restrict__ h1, float* __restrict__ h2,
    float* __restrict__ xp)
{
  __shared__ float sp4[4][512];
  const int w = threadIdx.x >> 6, lane = threadIdx.x & 63;
  const long row = (long)blockIdx.x * 4 + w;
  const long base = row * 512 + lane * 8;
  ushortx8 ux = *(const ushortx8*)(xb + base);
  ushortx8 ua = *(const ushortx8*)(aggA + base);
  ushortx8 ub = *(const ushortx8*)(aggB + base);
  float v[8];
  float s = 0.f;
#pragma unroll
  for (int k = 0; k < 8; ++k) {
    v[k] = b2f(ux[k]) + b2f(ua[k]) + b2f(ub[k]);
    s += v[k];
  }
#pragma unroll
  for (int msk = 1; msk <= 32; msk <<= 1) s += __shfl_xor(s, msk);
  float mean = s * (1.f / 512.f);
  float vv = 0.f;
#pragma unroll
  for (int k = 0; k < 8; ++k) { float d = v[k] - mean; vv += d * d; }
#pragma unroll
  for (int msk = 1; msk <= 32; msk <<= 1) vv += __shfl_xor(vv, msk);
  float inv = rsqrtf(vv * (1.f / 512.f) + 1e-5f);
  floatx4 o0, o1;
#pragma unroll
  for (int k = 0; k < 4; ++k) { v[k] = (v[k] - mean) * inv; o0[k] = v[k]; }
#pragma unroll
  for (int k = 0; k < 4; ++k) { v[4 + k] = (v[4 + k] - mean) * inv; o1[k] = v[4 + k]; }
  *(floatx4*)(out_x + base) = o0;
  *(floatx4*)(out_x + base + 4) = o1;
  *(floatx4*)(&sp4[w][lane * 8]) = o0;
  *(floatx4*)(&sp4[w][lane * 8 + 4]) = o1;
  __syncthreads();
  // block pool partial: sum of this block's 4 rows (256 blocks/batch)
  for (int t = threadIdx.x; t < 512; t += 256)
    xp[(long)blockIdx.x * 512 + t] =
        sp4[0][t] + sp4[1][t] + sp4[2][t] + sp4[3][t];
#pragma unroll
  for (int o = 0; o < 8; ++o) {
    const float* wp = (o == 0) ? Wcls
                    : (o <= 5) ? (Wdiff + (o - 1) * 512)
                    : (o == 6) ? Wpre : (Wpre + 512);
    floatx4 wa = *(const floatx4*)(wp + lane * 8);
    floatx4 wb = *(const floatx4*)(wp + lane * 8 + 4);
    float p = 0.f;
#pragma unroll
    for (int k = 0; k < 4; ++k) p += v[k] * wa[k];
#pragma unroll
    for (int k = 0; k < 4; ++k) p += v[4 + k] * wb[k];
#pragma unroll
    for (int msk = 1; msk <= 32; msk <<= 1) p += __shfl_xor(p, msk);
    if (lane == 0) {
      if (o == 0)      mastery[row] = p + bcls[0];
      else if (o <= 5) diff[row * 5 + (o - 1)] = p + bdiff[o - 1];
      else if (o == 6) h1[row] = p;
      else             h2[row] = p;
    }
  }
}

// =========================================================================
// epilogue: [0,8184) prereq as flat aligned float4 stream
//   (t = b*1047552 + i*1023 + pos; i,pos via const-div; j = pos + (pos>=i)),
// [8184,8248) xq partial pool reduce: xq[b*8+qg][c] = sum of 32 xp rows.
// =========================================================================
__global__ __launch_bounds__(256) void epi_kernel(
    const float* __restrict__ h1, const float* __restrict__ h2,
    const float* __restrict__ bpre, float* __restrict__ outp,
    const float* __restrict__ xp, float* __restrict__ xq)
{
  const int bid = blockIdx.x;
  if (bid < 8184) {
    const int g = bid * 256 + threadIdx.x;
    const int t = g * 4;                     // global fp32 index, 16B aligned
    const int b = t / 1047552;               // 1024*1023
    const int r = t - b * 1047552;
    const float bp = bpre[0];
    const float* h1b = h1 + b * 1024;
    const float* h2b = h2 + b * 1024;
    floatx4 o;
#pragma unroll
    for (int k = 0; k < 4; ++k) {
      int rk = r + k;                        // stays within batch (1047552%4==0)
      int i = rk / 1023;
      int pos = rk - i * 1023;
      int j = pos + (pos >= i);
      o[k] = h1b[i] + bp + h2b[j];
    }
    *(floatx4*)(outp + t) = o;
  } else {
    const int q0 = bid - 8184;               // (b,qg): b=q0>>3, qg=q0&7
    const float* p = xp + (long)q0 * 32 * 512;
#pragma unroll
    for (int cc = 0; cc < 2; ++cc) {
      int c = threadIdx.x + cc * 256;
      float s = 0.f;
#pragma unroll
      for (int q = 0; q < 32; ++q) s += p[q * 512 + c];
      xq[(long)q0 * 512 + c] = s;
    }
  }
}

// graph[b,o] = (sum_p xq[b*8+p][:]/1024) . WpT[:,o] + b_pool[o]
// 8 blocks x 256 thr; WpT access coalesced across lanes, xms LDS broadcast.
__global__ __launch_bounds__(256) void graph_kernel(
    const float* __restrict__ xq, const float* __restrict__ WpT,
    const float* __restrict__ bpool, float* __restrict__ g)
{
  __shared__ float xms[512];
  const int b = blockIdx.x;
  const float* xb = xq + (long)b * 8 * 512;
#pragma unroll
  for (int cc = 0; cc < 2; ++cc) {
    int c = threadIdx.x + cc * 256;
    float s = 0.f;
#pragma unroll
    for (int p = 0; p < 8; ++p) s += xb[p * 512 + c];
    xms[c] = s;
  }
  __syncthreads();
#pragma unroll
  for (int oo = 0; oo < 2; ++oo) {
    int o = threadIdx.x + oo * 256;
    float acc = 0.f;
    for (int h = 0; h < 512; ++h) acc += xms[h] * WpT[h * 512 + o];
    g[b * 512 + o] = acc * (1.f / 1024.f) + bpool[o];
  }
}

// =========================================================================
extern "C" void kernel_launch(void* const* d_in, const int* in_sizes, int n_in,
                              void* d_out, int out_size, void* d_ws, size_t ws_size,
                              hipStream_t stream)
{
  const float* CF    = (const float*)d_in[0];
  const float* ADJ   = (const float*)d_in[1];
  const float* Wemb  = (const float*)d_in[4];
  const float* bemb  = (const float*)d_in[5];
  const float* Win   = (const float*)d_in[6];
  const float* bin   = (const float*)d_in[7];
  const float* Wout  = (const float*)d_in[8];
  const float* bout  = (const float*)d_in[9];
  const float* Wconv = (const float*)d_in[10];
  const float* bconv = (const float*)d_in[11];
  const float* Wcls  = (const float*)d_in[12];
  const float* bcls  = (const float*)d_in[13];
  const float* Wdiff = (const float*)d_in[14];
  const float* bdiff = (const float*)d_in[15];
  const float* Wpre  = (const float*)d_in[16];
  const float* bpre  = (const float*)d_in[17];
  const float* Wpool = (const float*)d_in[18];
  const float* bpool = (const float*)d_in[19];

  // ---- workspace layout (ushort units). Total ~72 MB (< proven 84 MB). ----
  ushort_t* W = (ushort_t*)d_ws;
  ushort_t* xb   = W;                       // 4194304
  ushort_t* qkvb = W + 4194304;             // 12582912 (end 16777216)
  // aliases inside the qkv region (dead when their user runs):
  ushort_t* cT    = qkvb;                   // 4194304 (conv out, post-attn)
  ushort_t* aggA  = qkvb + 4194304;         // 4194304 (agg split-K part 0)
  ushort_t* aggB  = qkvb + 8388608;         // 4194304 (agg split-K part 1)
  // precompute scratch overlays aggA/B region (dead before qkv0 GEMM):
  ushort_t* WoT   = qkvb + 4194304;         // 786432
  ushort_t* Wcb   = qkvb + 4980736;         // 786432
  ushort_t* WembT = qkvb + 5767168;         // 131072 (end 5898240 < 8388608)
  // persistent:
  ushort_t* Winb = W + 16777216;            // 2359296
  ushort_t* Wfb  = W + 19136512;            // 786432 (fused Wconv@Wout)
  ushort_t* ADJb = W + 19922944;            // 8388608 (end 28311552)
  ushort_t* CFb  = W + 28311552;            // 4194304 (end 32505856)
  ushort_t* Wq0  = W + 32505856;            // 524288 (rows 0-511 Wemb, 512-2047 Win0@Wemb)
  float* bfused = (float*)(W + 33030144);   // 1536
  float* bcat   = bfused + 1536;            // 2048 (bemb ++ folded qkv0 bias)
  float* h1     = bcat + 2048;              // 8192
  float* h2     = h1 + 8192;                // 8192
  float* xp     = h2 + 8192;                // 1048576 (pool partials, 2048x512)
  float* xq     = xp + 1048576;             // 32768  (pool partials, 64x512)
  float* WpT    = xq + 32768;               // 262144 (Wpool transposed, fp32)

  // ---- output layout (fp32 concat) + d_out-as-scratch aliases ----
  float* out_x       = (float*)d_out;       // 4194304
  float* out_mastery = out_x + 4194304;     // 8192
  float* out_diff    = out_mastery + 8192;  // 40960
  float* out_prereq  = out_diff + 40960;    // 8380416
  float* out_graph   = out_prereq + 8380416;// 4096
  // attn-out bf16 scratch in out_x region (dead before final LN writes it):
  ushort_t* aob = (ushort_t*)out_x;         // 4194304 ushorts

  dim3 blk(256);

  // ---- precompute: one dispatch + one merged setup-GEMM dispatch ----
  prep_kernel<<<dim3(7778), blk, 0, stream>>>(
      Win, Winb, Wemb, Wq0, Wconv, Wcb, ADJ, ADJb, CF, CFb,
      Wout, WoT, bout, bconv, bfused, WembT, bemb, bin, bcat,
      Wpool, WpT);
  setup_gemm<<<dim3(24, 1, 4), blk, 0, stream>>>(
      Wcb, WoT, Wfb, Winb, WembT, Wq0 + 512 * 256);

  for (int l = 0; l < 3; ++l) {
    // qkv = x @ Win[l]^T + bin[l]   (128^2-tile GEMMs, 3 blocks/CU)
    if (l == 0) {
      // fused x0|qkv0: [xb | qkvb] = CFb @ Wq0^T + bcat  (8192 x 2048 x 256)
      gemm_bt<3, 1, 128><<<dim3(16, 64, 1), blk, 0, stream>>>(
          CFb, Wq0, bcat, xb, qkvb, 2048, 256, 0, 0, 0);
    } else {
      gemm_bt<1, 1, 128><<<dim3(12, 64, 1), blk, 0, stream>>>(
          xb, Winb + (long)l * 786432, bin + l * 1536,
          qkvb, nullptr, 1536, 512, 0, 0, 0);
    }
    // attention over batch axis -> aob (out_x scratch)
    attn_kernel<<<dim3(1024), dim3(512), 0, stream>>>(qkvb, aob);
    // convT = (ao @ Wfused[l]^T + bfused[l]) transposed, M-tile 64:
    // 512 blocks (was 256 = 1/CU, the provable occupancy outlier)
    gemm_bt<2, 1, 64><<<dim3(4, 128, 1), blk, 0, stream>>>(
        aob, Wfb + (long)l * 262144, bfused + l * 512,
        cT, nullptr, 512, 512, 0, 0, 0);
    // agg[b] = adj[b] @ conv[b]  (batched 1024x512x1024, split-K=2,
    // M-tile 64: 1024 blocks ~4/CU at IDENTICAL HBM traffic)
    gemm_bt<1, 2, 64><<<dim3(4, 16, 16), blk, 0, stream>>>(
        ADJb, cT, nullptr, aggA, aggB,
        512, 1024, 1048576, 524288, 524288);
    // x = LN(x + aggA + aggB)
    if (l < 2)
      ln_kernel<<<dim3(2048), blk, 0, stream>>>(xb, aggA, aggB, xb);
    else
      final_ln_heads_kernel<<<dim3(2048), blk, 0, stream>>>(
          xb, aggA, aggB, out_x, Wcls, bcls, Wdiff, bdiff, Wpre,
          out_mastery, out_diff, h1, h2, xp);
  }

  epi_kernel<<<dim3(8248), blk, 0, stream>>>(h1, h2, bpre, out_prereq,
                                             xp, xq);
  graph_kernel<<<dim3(8), blk, 0, stream>>>(xq, WpT, bpool, out_graph);
}